// Round 2
// baseline (1331.748 us; speedup 1.0000x reference)
//
#include <hip/hip_runtime.h>
#include <hip/hip_bf16.h>

// ---------------------------------------------------------------------------
// GIN0 (GINE x3 + BN + head) forward.
// R1: CSR + per-node register aggregation (no atomics in hot path).
// R3: node MLP GEMMs on MFMA via split-bf16 (hi+lo, 3-pass).
// R5: BN stats fused into GEMM2 epilogue; single prep kernel.
// R6: gathers read a bf16 copy of h; self-term fp32.
// R8: WPN waves/node; interleaved int2 CSR.
// R11: edge projection moved to MFMA. 16-edge groups: A = [ea_hi | ea_lo]
//      (K=32, precomputed bf16 hi/lo 'eab'), B1 = [Wh|Wh], B2 = [Wl|be rows],
//      C-init = gathered x_src (masked -1e30 on padded slots). Two
//      mfma_16x16x32_bf16 per 16ch-tile per 16 edges replace 32 pk_fma/edge.
//      We tiles staged in LDS; per-node cross-lane butterfly reduce.
// ---------------------------------------------------------------------------

typedef __attribute__((ext_vector_type(8))) short short8;
typedef __attribute__((ext_vector_type(4))) float floatx4;

__device__ __forceinline__ ushort f2bf_rne(float x) {
    unsigned u = __float_as_uint(x);
    unsigned r = (u + 0x7FFFu + ((u >> 16) & 1u)) >> 16;
    return (ushort)r;
}

__device__ __forceinline__ float bf2f(ushort u) {
    return __uint_as_float(((unsigned)u) << 16);
}

// ---------------- CSR build ----------------

__global__ __launch_bounds__(256) void hist_kernel(const int* __restrict__ dst,
                                                   int* __restrict__ deg, int E) {
    int i = blockIdx.x * blockDim.x + threadIdx.x;
    int stride = gridDim.x * blockDim.x;
    for (; i < E; i += stride) atomicAdd(&deg[dst[i]], 1);
}

__global__ __launch_bounds__(1024) void scan_kernel(const int* __restrict__ deg,
                                                    int* __restrict__ row_start, int N) {
    __shared__ int part[1024];
    int tid = threadIdx.x;
    int per = (N + 1023) / 1024;
    int start = tid * per;
    int end = min(start + per, N);
    int s = 0;
    for (int i = start; i < end; ++i) s += deg[i];
    part[tid] = s;
    __syncthreads();
    if (tid == 0) {
        int t = 0;
        for (int i = 0; i < 1024; ++i) {
            int v = part[i];
            part[i] = t;
            t += v;
        }
    }
    __syncthreads();
    int run = part[tid];
    for (int i = start; i < end; ++i) {
        row_start[i] = run;
        run += deg[i];
    }
    if (tid == 1023) row_start[N] = run;
}

__global__ __launch_bounds__(256) void scatter_kernel(
    const int* __restrict__ src, const int* __restrict__ dst,
    const int* __restrict__ row_start, int* __restrict__ cursor,
    int2* __restrict__ csr, int E) {
    int i = blockIdx.x * blockDim.x + threadIdx.x;
    int stride = gridDim.x * blockDim.x;
    for (; i < E; i += stride) {
        int v = dst[i];
        int p = row_start[v] + atomicAdd(&cursor[v], 1);
        csr[p] = make_int2(i, src[i]);
    }
}

// ---------------- Weight prep (node MLP GEMM weights) ----------------
__device__ __forceinline__ void wsplit(const float* W, ushort* Wth, ushort* Wtl,
                                       int K, int N, int t) {
    int k = t / N, n = t - k * N;
    float v = W[t];
    ushort hv = f2bf_rne(v);
    float hf = bf2f(hv);
    ushort lv = f2bf_rne(v - hf);
    Wth[(size_t)n * K + k] = hv;
    Wtl[(size_t)n * K + k] = lv;
}

__global__ __launch_bounds__(256) void prep_all(
    const float* W11, ushort* W11h, ushort* W11l,
    const float* W12, ushort* W12h, ushort* W12l,
    const float* W21, ushort* W21h, ushort* W21l,
    const float* W22, ushort* W22h, ushort* W22l,
    const float* W31, ushort* W31h, ushort* W31l,
    const float* W32, ushort* W32h, ushort* W32l) {
    int t = blockIdx.x * blockDim.x + threadIdx.x;
    const int s1 = 128 * 256, s2 = s1 + 256 * 256, s3 = s2 + 256 * 128;
    const int s4 = s3 + 128 * 128, s5 = s4 + 128 * 64, s6 = s5 + 64 * 64;
    if (t < s1) wsplit(W11, W11h, W11l, 128, 256, t);
    else if (t < s2) wsplit(W12, W12h, W12l, 256, 256, t - s1);
    else if (t < s3) wsplit(W21, W21h, W21l, 256, 128, t - s2);
    else if (t < s4) wsplit(W22, W22h, W22l, 128, 128, t - s3);
    else if (t < s5) wsplit(W31, W31h, W31l, 128, 64, t - s4);
    else if (t < s6) wsplit(W32, W32h, W32l, 64, 64, t - s5);
}

// ---------------- Edge-We prep: MFMA B-fragment layout -------------------
// Layout per layer: [tile][b][lane][8] bf16 ushorts, linear index
// ((t*2+b)*64 + l)*8 + j.  kq = (l>>4)*8+j, n = t*16 + (l&15).
// b=0 (B1): kq<16 -> Wh[kq][n]; kq>=16 -> Wh[kq-16][n]   (Wh | Wh)
// b=1 (B2): kq<16 -> Wl[kq][n]; kq==16 -> be_hi[n]; kq==17 -> be_lo[n]; else 0
__global__ __launch_bounds__(256) void prep_edgeW(
    const float* __restrict__ We1, const float* __restrict__ be1, ushort* __restrict__ O1,
    const float* __restrict__ We2, const float* __restrict__ be2, ushort* __restrict__ O2,
    const float* __restrict__ We3, const float* __restrict__ be3, ushort* __restrict__ O3) {
    int o = blockIdx.x * 256 + threadIdx.x;
    const int L1 = 8 * 2 * 512, L2e = L1 + 16 * 2 * 512, L3e = L2e + 8 * 2 * 512;
    const float* We;
    const float* be;
    ushort* out;
    int D, local;
    if (o < L1) { We = We1; be = be1; out = O1; D = 128; local = o; }
    else if (o < L2e) { We = We2; be = be2; out = O2; D = 256; local = o - L1; }
    else if (o < L3e) { We = We3; be = be3; out = O3; D = 128; local = o - L2e; }
    else return;
    int j = local & 7;
    int l = (local >> 3) & 63;
    int b = (local >> 9) & 1;
    int t = local >> 10;
    int kq = (l >> 4) * 8 + j;
    int n = t * 16 + (l & 15);
    int k = kq & 15;
    float w = We[k * D + n];
    ushort hv = f2bf_rne(w);
    ushort res;
    if (b == 0) {
        res = hv;  // Wh for both K-halves
    } else {
        if (kq < 16) {
            res = f2bf_rne(w - bf2f(hv));  // Wl
        } else if (kq == 16) {
            res = f2bf_rne(be[n]);  // be_hi
        } else if (kq == 17) {
            float bh = bf2f(f2bf_rne(be[n]));
            res = f2bf_rne(be[n] - bh);  // be_lo
        } else {
            res = 0;
        }
    }
    out[local] = res;
}

// ---------------- ea -> bf16 hi/lo rows (A-operand source) ----------------
// eab[e] = [hi[0..15], lo[0..15]] bf16 (64B per edge).
__global__ __launch_bounds__(256) void prep_eab(const float* __restrict__ ea,
                                                ushort* __restrict__ eab, int E) {
    int e = blockIdx.x * blockDim.x + threadIdx.x;
    int stride = gridDim.x * blockDim.x;
    for (; e < E; e += stride) {
        const float4* p = (const float4*)(ea + (size_t)e * 16);
        ushort hi[16], lo[16];
#pragma unroll
        for (int c4 = 0; c4 < 4; ++c4) {
            float4 v = p[c4];
            float vv[4] = {v.x, v.y, v.z, v.w};
#pragma unroll
            for (int r = 0; r < 4; ++r) {
                int d = c4 * 4 + r;
                ushort h = f2bf_rne(vv[r]);
                hi[d] = h;
                lo[d] = f2bf_rne(vv[r] - bf2f(h));
            }
        }
        unsigned w[16];
#pragma unroll
        for (int d = 0; d < 8; ++d) w[d] = (unsigned)hi[2 * d] | ((unsigned)hi[2 * d + 1] << 16);
#pragma unroll
        for (int d = 0; d < 8; ++d) w[8 + d] = (unsigned)lo[2 * d] | ((unsigned)lo[2 * d + 1] << 16);
        int4* o4 = (int4*)(eab + (size_t)e * 32);
        o4[0] = make_int4(w[0], w[1], w[2], w[3]);
        o4[1] = make_int4(w[4], w[5], w[6], w[7]);
        o4[2] = make_int4(w[8], w[9], w[10], w[11]);
        o4[3] = make_int4(w[12], w[13], w[14], w[15]);
    }
}

// ---------------- fp32 -> bf16 convert (layer-1 gather copy) --------------
__global__ __launch_bounds__(256) void f32_to_bf16(const float* __restrict__ in,
                                                   ushort* __restrict__ out, long n4) {
    long i = (long)blockIdx.x * blockDim.x + threadIdx.x;
    long stride = (long)gridDim.x * blockDim.x;
    for (; i < n4; i += stride) {
        float4 v = ((const float4*)in)[i];
        ushort4 o;
        o.x = f2bf_rne(v.x);
        o.y = f2bf_rne(v.y);
        o.z = f2bf_rne(v.z);
        o.w = f2bf_rne(v.w);
        ((ushort4*)out)[i] = o;
    }
}

// ---------------- Fused GINE aggregation (MFMA edge projection) -----------
// Per 16-edge group per wave: A1 = [eh|el] per edge (m = l&15 = edge slot),
// B from LDS (n = l&15 = channel), C-init = x_src (slot = (l>>4)*4+r),
// 2 mfma per 16-ch tile, relu+accumulate per slot; butterfly reduce per node.
template <int D, int WPN>
__global__ __launch_bounds__(256) void gine_agg_mfma(
    const float* __restrict__ h, const ushort* __restrict__ hb,
    const ushort* __restrict__ eab,
    const int* __restrict__ row_start, const int2* __restrict__ csr,
    const ushort* __restrict__ WeB,
    ushort* __restrict__ uhi, ushort* __restrict__ ulo, int N) {
    constexpr int NPB = 4 / WPN;          // nodes per 256-thread block
    constexpr int NT = D / (16 * WPN);    // 16-ch tiles per wave (=8)
    __shared__ ushort sW[(D / 16) * 2 * 512];

    const int tid = threadIdx.x;
    for (int s = tid; s < (D / 16) * 2 * 512 / 8; s += 256)
        ((int4*)sW)[s] = ((const int4*)WeB)[s];
    __syncthreads();

    const int lane = tid & 63;
    const int wid = tid >> 6;
    const int n16 = lane & 15;
    const int q = lane >> 4;
    const int q4 = q * 4;
    const bool hiq = q < 2;
    const int onesx = (q == 2) ? 0x3F803F80 : 0;  // bf16 1.0 at k=16,17
    const int chW = (wid % WPN) * 128;
    const ushort* sWl = sW + (size_t)(chW * 64) + lane * 8;  // wave tile base

    int v = blockIdx.x * NPB + wid / WPN;
    const int vstride = gridDim.x * NPB;
    const floatx4 z4 = (floatx4)0.f;

    for (; v < N; v += vstride) {
        const int e0 = row_start[v];
        const int e1 = row_start[v + 1];
        floatx4 macc[NT];
#pragma unroll
        for (int t = 0; t < NT; ++t) macc[t] = z4;

        auto body = [&](int2 c, int rem, bool tail) {
            // A operand: this lane's edge = slot n16
            short8 a1 = *(const short8*)&eab[(size_t)c.x * 32 + q * 8];
            int4 a1i = *reinterpret_cast<int4*>(&a1);
            int4 a2i;
            a2i.x = hiq ? a1i.x : onesx;
            a2i.y = hiq ? a1i.y : 0;
            a2i.z = hiq ? a1i.z : 0;
            a2i.w = hiq ? a1i.w : 0;
            short8 a2 = *reinterpret_cast<short8*>(&a2i);
            // x_src for this lane's 4 C-slots (q*4+r)
            int s0 = __shfl(c.y, q4 + 0);
            int s1 = __shfl(c.y, q4 + 1);
            int s2 = __shfl(c.y, q4 + 2);
            int s3 = __shfl(c.y, q4 + 3);
            const ushort* p0 = hb + (size_t)s0 * D + chW + n16;
            const ushort* p1 = hb + (size_t)s1 * D + chW + n16;
            const ushort* p2 = hb + (size_t)s2 * D + chW + n16;
            const ushort* p3 = hb + (size_t)s3 * D + chW + n16;
            unsigned xr0[NT], xr1[NT], xr2[NT], xr3[NT];
#pragma unroll
            for (int t = 0; t < NT; ++t) {
                xr0[t] = p0[t * 16];
                xr1[t] = p1[t * 16];
                xr2[t] = p2[t * 16];
                xr3[t] = p3[t * 16];
            }
            bool m0 = true, m1 = true, m2 = true, m3 = true;
            if (tail) {
                m0 = (q4 + 0) < rem;
                m1 = (q4 + 1) < rem;
                m2 = (q4 + 2) < rem;
                m3 = (q4 + 3) < rem;
            }
#pragma unroll
            for (int t = 0; t < NT; ++t) {
                floatx4 acc;
                acc[0] = __uint_as_float(xr0[t] << 16);
                acc[1] = __uint_as_float(xr1[t] << 16);
                acc[2] = __uint_as_float(xr2[t] << 16);
                acc[3] = __uint_as_float(xr3[t] << 16);
                if (tail) {  // padded slots -> -1e30 -> relu kills them
                    acc[0] = m0 ? acc[0] : -1e30f;
                    acc[1] = m1 ? acc[1] : -1e30f;
                    acc[2] = m2 ? acc[2] : -1e30f;
                    acc[3] = m3 ? acc[3] : -1e30f;
                }
                short8 b1 = *(const short8*)&sWl[t * 1024];
                short8 b2 = *(const short8*)&sWl[t * 1024 + 512];
                acc = __builtin_amdgcn_mfma_f32_16x16x32_bf16(a1, b1, acc, 0, 0, 0);
                acc = __builtin_amdgcn_mfma_f32_16x16x32_bf16(a2, b2, acc, 0, 0, 0);
                macc[t] += __builtin_elementwise_max(acc, z4);
            }
        };

        int i = e0;
        int rem = e1 - e0;
        if (rem > 0) {
            int2 c = csr[i + min(n16, rem - 1)];
            while (rem > 16) {  // full groups; prefetch next csr block
                int2 cn = csr[i + 16 + min(n16, rem - 17)];
                body(c, 16, false);
                c = cn;
                i += 16;
                rem -= 16;
            }
            body(c, rem, rem < 16);
        }

        // epilogue: butterfly-reduce 16 edge slots, u = h_v + agg -> bf16 hi/lo
#pragma unroll
        for (int t = 0; t < NT; ++t) {
            float s = macc[t][0] + macc[t][1] + macc[t][2] + macc[t][3];
            s += __shfl_xor(s, 16);
            s += __shfl_xor(s, 32);
            if (q == (t & 3)) {
                int ch = chW + t * 16 + n16;
                float u = h[(size_t)v * D + ch] + s;
                ushort h0 = f2bf_rne(u);
                ushort l0 = f2bf_rne(u - bf2f(h0));
                uhi[(size_t)v * D + ch] = h0;
                ulo[(size_t)v * D + ch] = l0;
            }
        }
    }
}

// ---------------- Split-bf16 MFMA GEMM (+ optional fused BN stats) ---------
template <int WRITE_BF16, int STATS>
__global__ __launch_bounds__(256) void gemm_mfma(
    const ushort* __restrict__ Ah, const ushort* __restrict__ Al,
    const ushort* __restrict__ Bh, const ushort* __restrict__ Bl,
    const float* __restrict__ bias,
    float* __restrict__ Cf, ushort* __restrict__ Chi, ushort* __restrict__ Clo,
    float* __restrict__ stats, int Nreal,
    int N, int K, int relu) {
    __shared__ ushort sA[2][128][72];
    __shared__ ushort sB[2][64][72];
    const int tid = threadIdx.x;
    const int wave = tid >> 6, lane = tid & 63;
    const int lrow = lane & 15, lquad = lane >> 4;
    const int bm = blockIdx.y * 128;
    const int bn = blockIdx.x * 64;

    floatx4 acc[2][4];
#pragma unroll
    for (int i = 0; i < 2; ++i)
#pragma unroll
        for (int j = 0; j < 4; ++j) acc[i][j] = (floatx4)0.f;

    for (int k0 = 0; k0 < K; k0 += 64) {
        for (int s = tid; s < 1024; s += 256) {
            int row = s >> 3, c8 = (s & 7) * 8;
            size_t g = (size_t)(bm + row) * K + k0 + c8;
            *(int4*)&sA[0][row][c8] = *(const int4*)&Ah[g];
            *(int4*)&sA[1][row][c8] = *(const int4*)&Al[g];
        }
        for (int s = tid; s < 512; s += 256) {
            int row = s >> 3, c8 = (s & 7) * 8;
            size_t g = (size_t)(bn + row) * K + k0 + c8;
            *(int4*)&sB[0][row][c8] = *(const int4*)&Bh[g];
            *(int4*)&sB[1][row][c8] = *(const int4*)&Bl[g];
        }
        __syncthreads();
        const int rb = wave * 32;
#pragma unroll
        for (int kk = 0; kk < 2; ++kk) {
            int ko = kk * 32 + lquad * 8;
            short8 ah[2], al[2], bh[4], bl[4];
#pragma unroll
            for (int i = 0; i < 2; ++i) {
                ah[i] = *(const short8*)&sA[0][rb + i * 16 + lrow][ko];
                al[i] = *(const short8*)&sA[1][rb + i * 16 + lrow][ko];
            }
#pragma unroll
            for (int j = 0; j < 4; ++j) {
                bh[j] = *(const short8*)&sB[0][j * 16 + lrow][ko];
                bl[j] = *(const short8*)&sB[1][j * 16 + lrow][ko];
            }
#pragma unroll
            for (int i = 0; i < 2; ++i)
#pragma unroll
                for (int j = 0; j < 4; ++j) {
                    acc[i][j] = __builtin_amdgcn_mfma_f32_16x16x32_bf16(
                        ah[i], bh[j], acc[i][j], 0, 0, 0);
                    acc[i][j] = __builtin_amdgcn_mfma_f32_16x16x32_bf16(
                        ah[i], bl[j], acc[i][j], 0, 0, 0);
                    acc[i][j] = __builtin_amdgcn_mfma_f32_16x16x32_bf16(
                        al[i], bh[j], acc[i][j], 0, 0, 0);
                }
        }
        __syncthreads();
    }
    float sj[4] = {0.f, 0.f, 0.f, 0.f};
    float qj[4] = {0.f, 0.f, 0.f, 0.f};
#pragma unroll
    for (int i = 0; i < 2; ++i)
#pragma unroll
        for (int j = 0; j < 4; ++j) {
            int gc = bn + j * 16 + lrow;
            float bv = bias[gc];
#pragma unroll
            for (int r = 0; r < 4; ++r) {
                int gr = bm + wave * 32 + i * 16 + lquad * 4 + r;
                float v = acc[i][j][r] + bv;
                if (relu) v = fmaxf(v, 0.f);
                if (STATS && gr < Nreal) {
                    sj[j] += v;
                    qj[j] = fmaf(v, v, qj[j]);
                }
                if (WRITE_BF16) {
                    ushort hv = f2bf_rne(v);
                    ushort lv = f2bf_rne(v - bf2f(hv));
                    Chi[(size_t)gr * N + gc] = hv;
                    Clo[(size_t)gr * N + gc] = lv;
                } else {
                    Cf[(size_t)gr * N + gc] = v;
                }
            }
        }
    if (STATS) {
#pragma unroll
        for (int j = 0; j < 4; ++j) {
            float s = sj[j], q = qj[j];
            s += __shfl_xor(s, 16);
            s += __shfl_xor(s, 32);
            q += __shfl_xor(q, 16);
            q += __shfl_xor(q, 32);
            if (lquad == 0) {
                int gc = bn + j * 16 + lrow;
                atomicAdd(&stats[gc], s);
                atomicAdd(&stats[N + gc], q);
            }
        }
    }
}

// ---------------- BatchNorm apply (vectorized, + bf16 copy) ----------------
__global__ __launch_bounds__(256) void bn_apply_kernel(
    const float* __restrict__ r, float* __restrict__ h,
    ushort* __restrict__ hbout,
    const float* __restrict__ sums,
    const float* __restrict__ g, const float* __restrict__ bt,
    int N, int D, int Dm1) {
    int idx = blockIdx.x * blockDim.x + threadIdx.x;
    int total4 = N * D / 4;
    int stride = gridDim.x * blockDim.x;
    float invN = 1.0f / (float)N;
    for (; idx < total4; idx += stride) {
        int c = (idx * 4) & Dm1;
        float4 s4 = *(const float4*)&sums[c];
        float4 q4 = *(const float4*)&sums[D + c];
        float4 g4 = *(const float4*)&g[c];
        float4 b4 = *(const float4*)&bt[c];
        float4 r4 = ((const float4*)r)[idx];
        float4 o;
        {
            float mu = s4.x * invN;
            float var = fmaf(-mu, mu, q4.x * invN);
            o.x = (r4.x - mu) * (rsqrtf(var + 1e-5f) * g4.x) + b4.x;
            mu = s4.y * invN;
            var = fmaf(-mu, mu, q4.y * invN);
            o.y = (r4.y - mu) * (rsqrtf(var + 1e-5f) * g4.y) + b4.y;
            mu = s4.z * invN;
            var = fmaf(-mu, mu, q4.z * invN);
            o.z = (r4.z - mu) * (rsqrtf(var + 1e-5f) * g4.z) + b4.z;
            mu = s4.w * invN;
            var = fmaf(-mu, mu, q4.w * invN);
            o.w = (r4.w - mu) * (rsqrtf(var + 1e-5f) * g4.w) + b4.w;
        }
        ((float4*)h)[idx] = o;
        if (hbout) {
            ushort4 ob;
            ob.x = f2bf_rne(o.x);
            ob.y = f2bf_rne(o.y);
            ob.z = f2bf_rne(o.z);
            ob.w = f2bf_rne(o.w);
            ((ushort4*)hbout)[idx] = ob;
        }
    }
}

// ---------------- Head ----------------
__global__ void head_kernel(const float* __restrict__ h, const int* __restrict__ n_nodes,
                            const float* __restrict__ Wf1, const float* __restrict__ bf1,
                            const float* __restrict__ Wf2, const float* __restrict__ bf2,
                            float* __restrict__ out, int G) {
    int g = blockIdx.x * blockDim.x + threadIdx.x;
    if (g >= G) return;
    int s = 0;
    for (int i = 0; i <= g; ++i) s += n_nodes[i];
    const float* m = &h[(size_t)(s - 1) * 64];
    float o = bf2[0];
#pragma unroll 4
    for (int j = 0; j < 16; ++j) {
        float acc = bf1[j];
        for (int k = 0; k < 64; ++k) acc = fmaf(m[k], Wf1[k * 16 + j], acc);
        acc = fmaxf(acc, 0.f);
        o = fmaf(acc, Wf2[j], o);
    }
    out[g] = o;
}

extern "C" void kernel_launch(void* const* d_in, const int* in_sizes, int n_in,
                              void* d_out, int out_size, void* d_ws, size_t ws_size,
                              hipStream_t stream) {
    const float* x = (const float*)d_in[0];
    const float* ea = (const float*)d_in[1];
    const int* eidx = (const int*)d_in[2];
    const int* n_nodes = (const int*)d_in[3];
    const float* We1 = (const float*)d_in[4];
    const float* be1 = (const float*)d_in[5];
    const float* W11 = (const float*)d_in[6];
    const float* b11 = (const float*)d_in[7];
    const float* W12 = (const float*)d_in[8];
    const float* b12 = (const float*)d_in[9];
    const float* g1 = (const float*)d_in[10];
    const float* bt1 = (const float*)d_in[11];
    const float* We2 = (const float*)d_in[12];
    const float* be2 = (const float*)d_in[13];
    const float* W21 = (const float*)d_in[14];
    const float* b21 = (const float*)d_in[15];
    const float* W22 = (const float*)d_in[16];
    const float* b22 = (const float*)d_in[17];
    const float* g2 = (const float*)d_in[18];
    const float* bt2 = (const float*)d_in[19];
    const float* We3 = (const float*)d_in[20];
    const float* be3 = (const float*)d_in[21];
    const float* W31 = (const float*)d_in[22];
    const float* b31 = (const float*)d_in[23];
    const float* W32 = (const float*)d_in[24];
    const float* b32 = (const float*)d_in[25];
    const float* g3 = (const float*)d_in[26];
    const float* bt3 = (const float*)d_in[27];
    const float* Wf1 = (const float*)d_in[28];
    const float* bf1 = (const float*)d_in[29];
    const float* Wf2 = (const float*)d_in[30];
    const float* bf2 = (const float*)d_in[31];

    const int N = in_sizes[0] / 128;  // 50000
    const int E = in_sizes[2] / 2;    // 800000
    const int G = in_sizes[3];        // 500
    const int Mp = ((N + 127) / 128) * 128;  // 50048
    const int* srcp = eidx;
    const int* dstp = eidx + E;

    float* H = (float*)d_ws;            // Mp x 256 fp32
    float* UR = H + (size_t)Mp * 256;   // Mp x 256: u(hi/lo bf16) / r(fp32)
    float* TT = UR + (size_t)Mp * 256;  // Mp x 256: t(hi/lo bf16) / hb(bf16)
    float* stats1 = TT + (size_t)Mp * 256;  // 512
    float* stats2 = stats1 + 512;           // 256
    float* stats3 = stats2 + 256;           // 128
    int* deg = (int*)(stats3 + 128);        // N
    int* cursor = deg + N;                  // N
    int* row_start = cursor + N;            // N+1 (+1 pad for int2 align)
    int2* csr = (int2*)(row_start + N + 2); // E int2
    size_t woff = (size_t)((int*)(csr + E) - (int*)d_ws);
    woff = (woff + 3) & ~(size_t)3;
    ushort* wp = (ushort*)((int*)d_ws + woff);
    ushort* W11th = wp; wp += 128 * 256;
    ushort* W11tl = wp; wp += 128 * 256;
    ushort* W12th = wp; wp += 256 * 256;
    ushort* W12tl = wp; wp += 256 * 256;
    ushort* W21th = wp; wp += 256 * 128;
    ushort* W21tl = wp; wp += 256 * 128;
    ushort* W22th = wp; wp += 128 * 128;
    ushort* W22tl = wp; wp += 128 * 128;
    ushort* W31th = wp; wp += 128 * 64;
    ushort* W31tl = wp; wp += 128 * 64;
    ushort* W32th = wp; wp += 64 * 64;
    ushort* W32tl = wp; wp += 64 * 64;
    ushort* WeB1 = wp; wp += 8 * 2 * 512;    // edge-We MFMA frags L1
    ushort* WeB2 = wp; wp += 16 * 2 * 512;   // L2
    ushort* WeB3 = wp; wp += 8 * 2 * 512;    // L3
    // align eab to 16B
    {
        size_t off = (size_t)(wp - (ushort*)d_ws);
        off = (off + 7) & ~(size_t)7;
        wp = (ushort*)d_ws + off;
    }
    ushort* eab = wp;  // E x 32 bf16 (hi16|lo16) = 51.2 MB

    hipMemsetAsync(stats1, 0, 896 * sizeof(float) + (size_t)2 * N * sizeof(int), stream);

    const int prepTot = 128 * 256 + 256 * 256 + 256 * 128 + 128 * 128 + 128 * 64 + 64 * 64;
    prep_all<<<(prepTot + 255) / 256, 256, 0, stream>>>(
        W11, W11th, W11tl, W12, W12th, W12tl, W21, W21th, W21tl,
        W22, W22th, W22tl, W31, W31th, W31tl, W32, W32th, W32tl);
    prep_edgeW<<<(32 * 2 * 512 + 255) / 256, 256, 0, stream>>>(
        We1, be1, WeB1, We2, be2, WeB2, We3, be3, WeB3);
    prep_eab<<<3125, 256, 0, stream>>>(ea, eab, E);

    hist_kernel<<<3125, 256, 0, stream>>>(dstp, deg, E);
    scan_kernel<<<1, 1024, 0, stream>>>(deg, row_start, N);
    scatter_kernel<<<3125, 256, 0, stream>>>(srcp, dstp, row_start, cursor, csr, E);

    const int gy = Mp / 128;
    float* R = UR;
    ushort* HB = (ushort*)TT;  // bf16 gather copy lives in the (dead) TT region

    // ---------------- Layer 1: 128 -> 256 -> 256 ----------------
    {
        ushort* Uhi = (ushort*)UR; ushort* Ulo = Uhi + (size_t)Mp * 128;
        ushort* Thi = (ushort*)TT; ushort* Tlo = Thi + (size_t)Mp * 256;
        f32_to_bf16<<<2048, 256, 0, stream>>>(x, HB, (long)N * 128 / 4);
        gine_agg_mfma<128, 1><<<(N + 3) / 4, 256, 0, stream>>>(
            x, HB, eab, row_start, csr, WeB1, Uhi, Ulo, N);
        gemm_mfma<1, 0><<<dim3(4, gy), 256, 0, stream>>>(
            Uhi, Ulo, W11th, W11tl, b11, nullptr, Thi, Tlo, nullptr, 0, 256, 128, 1);
        gemm_mfma<0, 1><<<dim3(4, gy), 256, 0, stream>>>(
            Thi, Tlo, W12th, W12tl, b12, R, nullptr, nullptr, stats1, N, 256, 256, 1);
        bn_apply_kernel<<<2048, 256, 0, stream>>>(R, H, HB, stats1, g1, bt1, N, 256, 255);
    }

    // ---------------- Layer 2: 256 -> 128 -> 128 ----------------
    {
        ushort* Uhi = (ushort*)UR; ushort* Ulo = Uhi + (size_t)Mp * 256;
        ushort* Thi = (ushort*)TT; ushort* Tlo = Thi + (size_t)Mp * 128;
        gine_agg_mfma<256, 2><<<(N + 1) / 2, 256, 0, stream>>>(
            H, HB, eab, row_start, csr, WeB2, Uhi, Ulo, N);
        gemm_mfma<1, 0><<<dim3(2, gy), 256, 0, stream>>>(
            Uhi, Ulo, W21th, W21tl, b21, nullptr, Thi, Tlo, nullptr, 0, 128, 256, 1);
        gemm_mfma<0, 1><<<dim3(2, gy), 256, 0, stream>>>(
            Thi, Tlo, W22th, W22tl, b22, R, nullptr, nullptr, stats2, N, 128, 128, 1);
        bn_apply_kernel<<<2048, 256, 0, stream>>>(R, H, HB, stats2, g2, bt2, N, 128, 127);
    }

    // ---------------- Layer 3: 128 -> 64 -> 64 ----------------
    {
        ushort* Uhi = (ushort*)UR; ushort* Ulo = Uhi + (size_t)Mp * 128;
        ushort* Thi = (ushort*)TT; ushort* Tlo = Thi + (size_t)Mp * 64;
        gine_agg_mfma<128, 1><<<(N + 3) / 4, 256, 0, stream>>>(
            H, HB, eab, row_start, csr, WeB3, Uhi, Ulo, N);
        gemm_mfma<1, 0><<<dim3(1, gy), 256, 0, stream>>>(
            Uhi, Ulo, W31th, W31tl, b31, nullptr, Thi, Tlo, nullptr, 0, 64, 128, 1);
        gemm_mfma<0, 1><<<dim3(1, gy), 256, 0, stream>>>(
            Thi, Tlo, W32th, W32tl, b32, R, nullptr, nullptr, stats3, N, 64, 64, 1);
        bn_apply_kernel<<<2048, 256, 0, stream>>>(R, H, nullptr, stats3, g3, bt3, N, 64, 63);
    }

    // ---------------- Head ----------------
    head_kernel<<<(G + 255) / 256, 256, 0, stream>>>(H, n_nodes, Wf1, bf1, Wf2, bf2,
                                                     (float*)d_out, G);
}

// Round 3
// 1301.167 us; speedup vs baseline: 1.0235x; 1.0235x over previous
//
#include <hip/hip_runtime.h>
#include <hip/hip_bf16.h>

// ---------------------------------------------------------------------------
// GIN0 (GINE x3 + BN + head) forward.
// R1: CSR + per-node register aggregation (no atomics in hot path).
// R3: node MLP GEMMs on MFMA via split-bf16 (hi+lo, 3-pass).
// R5: BN stats fused into GEMM2 epilogue; single prep kernel.
// R6: gathers read a bf16 copy of h; self-term fp32.
// R8: WPN waves/node; interleaved int2 CSR.
// R12: MFMA edge projection, transposed mapping. A = We (M=channels,
//      loop-invariant, VGPR-resident, no LDS), B = 16 edge slots (N side,
//      lane-local eab reads), C-init = x_src + be (lane-local 8B gathers,
//      4 consecutive channels/lane). Two mfma per 16ch-tile per 16 edges,
//      one shared A-frag (bias via C-init, not a second A). Butterfly
//      reduce over edge slots per node. No shuffles/readlanes in body.
// ---------------------------------------------------------------------------

typedef __attribute__((ext_vector_type(8))) short short8;
typedef __attribute__((ext_vector_type(4))) float floatx4;

__device__ __forceinline__ ushort f2bf_rne(float x) {
    unsigned u = __float_as_uint(x);
    unsigned r = (u + 0x7FFFu + ((u >> 16) & 1u)) >> 16;
    return (ushort)r;
}

__device__ __forceinline__ float bf2f(ushort u) {
    return __uint_as_float(((unsigned)u) << 16);
}

// ---------------- CSR build ----------------

__global__ __launch_bounds__(256) void hist_kernel(const int* __restrict__ dst,
                                                   int* __restrict__ deg, int E) {
    int i = blockIdx.x * blockDim.x + threadIdx.x;
    int stride = gridDim.x * blockDim.x;
    for (; i < E; i += stride) atomicAdd(&deg[dst[i]], 1);
}

__global__ __launch_bounds__(1024) void scan_kernel(const int* __restrict__ deg,
                                                    int* __restrict__ row_start, int N) {
    __shared__ int part[1024];
    int tid = threadIdx.x;
    int per = (N + 1023) / 1024;
    int start = tid * per;
    int end = min(start + per, N);
    int s = 0;
    for (int i = start; i < end; ++i) s += deg[i];
    part[tid] = s;
    __syncthreads();
    if (tid == 0) {
        int t = 0;
        for (int i = 0; i < 1024; ++i) {
            int v = part[i];
            part[i] = t;
            t += v;
        }
    }
    __syncthreads();
    int run = part[tid];
    for (int i = start; i < end; ++i) {
        row_start[i] = run;
        run += deg[i];
    }
    if (tid == 1023) row_start[N] = run;
}

__global__ __launch_bounds__(256) void scatter_kernel(
    const int* __restrict__ src, const int* __restrict__ dst,
    const int* __restrict__ row_start, int* __restrict__ cursor,
    int2* __restrict__ csr, int E) {
    int i = blockIdx.x * blockDim.x + threadIdx.x;
    int stride = gridDim.x * blockDim.x;
    for (; i < E; i += stride) {
        int v = dst[i];
        int p = row_start[v] + atomicAdd(&cursor[v], 1);
        csr[p] = make_int2(i, src[i]);
    }
}

// ---------------- Weight prep (node MLP GEMM weights) ----------------
__device__ __forceinline__ void wsplit(const float* W, ushort* Wth, ushort* Wtl,
                                       int K, int N, int t) {
    int k = t / N, n = t - k * N;
    float v = W[t];
    ushort hv = f2bf_rne(v);
    float hf = bf2f(hv);
    ushort lv = f2bf_rne(v - hf);
    Wth[(size_t)n * K + k] = hv;
    Wtl[(size_t)n * K + k] = lv;
}

__global__ __launch_bounds__(256) void prep_all(
    const float* W11, ushort* W11h, ushort* W11l,
    const float* W12, ushort* W12h, ushort* W12l,
    const float* W21, ushort* W21h, ushort* W21l,
    const float* W22, ushort* W22h, ushort* W22l,
    const float* W31, ushort* W31h, ushort* W31l,
    const float* W32, ushort* W32h, ushort* W32l) {
    int t = blockIdx.x * blockDim.x + threadIdx.x;
    const int s1 = 128 * 256, s2 = s1 + 256 * 256, s3 = s2 + 256 * 128;
    const int s4 = s3 + 128 * 128, s5 = s4 + 128 * 64, s6 = s5 + 64 * 64;
    if (t < s1) wsplit(W11, W11h, W11l, 128, 256, t);
    else if (t < s2) wsplit(W12, W12h, W12l, 256, 256, t - s1);
    else if (t < s3) wsplit(W21, W21h, W21l, 256, 128, t - s2);
    else if (t < s4) wsplit(W22, W22h, W22l, 128, 128, t - s3);
    else if (t < s5) wsplit(W31, W31h, W31l, 128, 64, t - s4);
    else if (t < s6) wsplit(W32, W32h, W32l, 64, 64, t - s5);
}

// ---------------- Edge-We prep: MFMA A-fragment layout -------------------
// Per layer: [tile][lane][8] ushort; lane l holds A[m=l&15][k=(l>>4)*8+j]
// over K=32 = [Wh(16) | Wl(16)], m = channel-in-tile, value We[k&15][ch].
__global__ __launch_bounds__(256) void prep_edgeWA(
    const float* __restrict__ We1, ushort* __restrict__ O1,
    const float* __restrict__ We2, ushort* __restrict__ O2,
    const float* __restrict__ We3, ushort* __restrict__ O3) {
    int o = blockIdx.x * 256 + threadIdx.x;
    const int L1 = 8 * 512, L2e = L1 + 16 * 512, L3e = L2e + 8 * 512;
    const float* We;
    ushort* out;
    int D, local;
    if (o < L1) { We = We1; out = O1; D = 128; local = o; }
    else if (o < L2e) { We = We2; out = O2; D = 256; local = o - L1; }
    else if (o < L3e) { We = We3; out = O3; D = 128; local = o - L2e; }
    else return;
    int j = local & 7;
    int l = (local >> 3) & 63;
    int t = local >> 9;
    int k = (l >> 4) * 8 + j;
    int ch = t * 16 + (l & 15);
    float w = We[(k & 15) * D + ch];
    ushort hv = f2bf_rne(w);
    out[local] = (k < 16) ? hv : f2bf_rne(w - bf2f(hv));
}

// ---------------- ea -> bf16 hi/lo rows (B-operand source) ----------------
// eab[e] = [hi[0..15], lo[0..15]] bf16 (64B per edge).
__global__ __launch_bounds__(256) void prep_eab(const float* __restrict__ ea,
                                                ushort* __restrict__ eab, int E) {
    int e = blockIdx.x * blockDim.x + threadIdx.x;
    int stride = gridDim.x * blockDim.x;
    for (; e < E; e += stride) {
        const float4* p = (const float4*)(ea + (size_t)e * 16);
        ushort hi[16], lo[16];
#pragma unroll
        for (int c4 = 0; c4 < 4; ++c4) {
            float4 v = p[c4];
            float vv[4] = {v.x, v.y, v.z, v.w};
#pragma unroll
            for (int r = 0; r < 4; ++r) {
                int d = c4 * 4 + r;
                ushort h = f2bf_rne(vv[r]);
                hi[d] = h;
                lo[d] = f2bf_rne(vv[r] - bf2f(h));
            }
        }
        unsigned w[16];
#pragma unroll
        for (int d = 0; d < 8; ++d) w[d] = (unsigned)hi[2 * d] | ((unsigned)hi[2 * d + 1] << 16);
#pragma unroll
        for (int d = 0; d < 8; ++d) w[8 + d] = (unsigned)lo[2 * d] | ((unsigned)lo[2 * d + 1] << 16);
        int4* o4 = (int4*)(eab + (size_t)e * 32);
        o4[0] = make_int4(w[0], w[1], w[2], w[3]);
        o4[1] = make_int4(w[4], w[5], w[6], w[7]);
        o4[2] = make_int4(w[8], w[9], w[10], w[11]);
        o4[3] = make_int4(w[12], w[13], w[14], w[15]);
    }
}

// ---------------- fp32 -> bf16 convert (layer-1 gather copy) --------------
__global__ __launch_bounds__(256) void f32_to_bf16(const float* __restrict__ in,
                                                   ushort* __restrict__ out, long n4) {
    long i = (long)blockIdx.x * blockDim.x + threadIdx.x;
    long stride = (long)gridDim.x * blockDim.x;
    for (; i < n4; i += stride) {
        float4 v = ((const float4*)in)[i];
        ushort4 o;
        o.x = f2bf_rne(v.x);
        o.y = f2bf_rne(v.y);
        o.z = f2bf_rne(v.z);
        o.w = f2bf_rne(v.w);
        ((ushort4*)out)[i] = o;
    }
}

// ---------------- Fused GINE aggregation (MFMA, transposed mapping) -------
// A = We frag (M=channels, registers), B = 16 edge slots (N, lane-local),
// C[m=q*4+r][n=n16]: lane (q,n16) owns 4 consecutive channels of edge n16.
// mfma1: A=[Wh|Wl] x B1=[eh|eh]; mfma2: A x B2=[el|0]; C-init = x_src + be.
template <int D, int WPN>
__global__ __launch_bounds__(256) void gine_agg_mfma(
    const float* __restrict__ h, const ushort* __restrict__ hb,
    const ushort* __restrict__ eab,
    const int* __restrict__ row_start, const int2* __restrict__ csr,
    const ushort* __restrict__ WeA, const float* __restrict__ be,
    ushort* __restrict__ uhi, ushort* __restrict__ ulo, int N) {
    constexpr int NPB = 4 / WPN;    // nodes per 256-thread block
    constexpr int CPW = D / WPN;    // channels per wave
    constexpr int NT = CPW / 16;    // 16-ch tiles per wave
    const int tid = threadIdx.x;
    const int lane = tid & 63;
    const int wid = tid >> 6;
    const int n16 = lane & 15;
    const int q = lane >> 4;
    const int chW = (wid % WPN) * CPW;

    short8 a[NT];
    floatx4 bev[NT];
#pragma unroll
    for (int t = 0; t < NT; ++t) {
        a[t] = *(const short8*)&WeA[((chW / 16 + t) * 64 + lane) * 8];
        bev[t] = *(const floatx4*)&be[chW + t * 16 + q * 4];
    }

    int v = blockIdx.x * NPB + wid / WPN;
    const int vstride = gridDim.x * NPB;
    const floatx4 z4 = (floatx4)0.f;

    for (; v < N; v += vstride) {
        const int e0 = row_start[v];
        const int e1 = row_start[v + 1];
        floatx4 macc[NT];
#pragma unroll
        for (int t = 0; t < NT; ++t) macc[t] = z4;

        auto body = [&](int2 c, int rem, bool tail) {
            const ushort* ebase = eab + (size_t)c.x * 32;
            short8 b1 = *(const short8*)&ebase[(q & 1) * 8];
            int4 b2i = *(const int4*)&ebase[16 + (q & 1) * 8];
            if (q >= 2) { b2i.x = 0; b2i.y = 0; b2i.z = 0; b2i.w = 0; }
            short8 b2 = *reinterpret_cast<short8*>(&b2i);
            const ushort* hp = hb + (size_t)c.y * D + chW + q * 4;
            uint2 xr[NT];
#pragma unroll
            for (int t = 0; t < NT; ++t) xr[t] = *(const uint2*)&hp[t * 16];
            const bool pad = tail && (n16 >= rem);
#pragma unroll
            for (int t = 0; t < NT; ++t) {
                floatx4 acc;
                acc[0] = __uint_as_float(xr[t].x << 16);
                acc[1] = __uint_as_float(xr[t].x & 0xffff0000u);
                acc[2] = __uint_as_float(xr[t].y << 16);
                acc[3] = __uint_as_float(xr[t].y & 0xffff0000u);
                acc += bev[t];
                if (pad) {  // padded edge slots -> -1e30 -> relu kills them
                    acc[0] = -1e30f; acc[1] = -1e30f;
                    acc[2] = -1e30f; acc[3] = -1e30f;
                }
                acc = __builtin_amdgcn_mfma_f32_16x16x32_bf16(a[t], b1, acc, 0, 0, 0);
                acc = __builtin_amdgcn_mfma_f32_16x16x32_bf16(a[t], b2, acc, 0, 0, 0);
                macc[t] += __builtin_elementwise_max(acc, z4);
            }
        };

        int i = e0;
        int rem = e1 - e0;
        if (rem > 0) {
            int2 c = csr[i + min(n16, rem - 1)];
            while (rem > 16) {  // full groups; prefetch next csr block
                int2 cn = csr[i + 16 + min(n16, rem - 17)];
                body(c, 16, false);
                c = cn;
                i += 16;
                rem -= 16;
            }
            body(c, rem, rem < 16);
        }

        // epilogue: butterfly-reduce 16 edge slots, u = h_v + agg -> bf16 hi/lo
#pragma unroll
        for (int t = 0; t < NT; ++t) {
            floatx4 s = macc[t];
#pragma unroll
            for (int m = 1; m < 16; m <<= 1) {
                s[0] += __shfl_xor(s[0], m);
                s[1] += __shfl_xor(s[1], m);
                s[2] += __shfl_xor(s[2], m);
                s[3] += __shfl_xor(s[3], m);
            }
            if (n16 == 0) {
                const int ch = chW + t * 16 + q * 4;
                float4 hv4 = *(const float4*)&h[(size_t)v * D + ch];
                float u0 = hv4.x + s[0], u1 = hv4.y + s[1];
                float u2 = hv4.z + s[2], u3 = hv4.w + s[3];
                ushort h0 = f2bf_rne(u0), h1 = f2bf_rne(u1);
                ushort h2 = f2bf_rne(u2), h3 = f2bf_rne(u3);
                *(ushort4*)&uhi[(size_t)v * D + ch] = make_ushort4(h0, h1, h2, h3);
                *(ushort4*)&ulo[(size_t)v * D + ch] = make_ushort4(
                    f2bf_rne(u0 - bf2f(h0)), f2bf_rne(u1 - bf2f(h1)),
                    f2bf_rne(u2 - bf2f(h2)), f2bf_rne(u3 - bf2f(h3)));
            }
        }
    }
}

// ---------------- Split-bf16 MFMA GEMM (+ optional fused BN stats) ---------
template <int WRITE_BF16, int STATS>
__global__ __launch_bounds__(256) void gemm_mfma(
    const ushort* __restrict__ Ah, const ushort* __restrict__ Al,
    const ushort* __restrict__ Bh, const ushort* __restrict__ Bl,
    const float* __restrict__ bias,
    float* __restrict__ Cf, ushort* __restrict__ Chi, ushort* __restrict__ Clo,
    float* __restrict__ stats, int Nreal,
    int N, int K, int relu) {
    __shared__ ushort sA[2][128][72];
    __shared__ ushort sB[2][64][72];
    const int tid = threadIdx.x;
    const int wave = tid >> 6, lane = tid & 63;
    const int lrow = lane & 15, lquad = lane >> 4;
    const int bm = blockIdx.y * 128;
    const int bn = blockIdx.x * 64;

    floatx4 acc[2][4];
#pragma unroll
    for (int i = 0; i < 2; ++i)
#pragma unroll
        for (int j = 0; j < 4; ++j) acc[i][j] = (floatx4)0.f;

    for (int k0 = 0; k0 < K; k0 += 64) {
        for (int s = tid; s < 1024; s += 256) {
            int row = s >> 3, c8 = (s & 7) * 8;
            size_t g = (size_t)(bm + row) * K + k0 + c8;
            *(int4*)&sA[0][row][c8] = *(const int4*)&Ah[g];
            *(int4*)&sA[1][row][c8] = *(const int4*)&Al[g];
        }
        for (int s = tid; s < 512; s += 256) {
            int row = s >> 3, c8 = (s & 7) * 8;
            size_t g = (size_t)(bn + row) * K + k0 + c8;
            *(int4*)&sB[0][row][c8] = *(const int4*)&Bh[g];
            *(int4*)&sB[1][row][c8] = *(const int4*)&Bl[g];
        }
        __syncthreads();
        const int rb = wave * 32;
#pragma unroll
        for (int kk = 0; kk < 2; ++kk) {
            int ko = kk * 32 + lquad * 8;
            short8 ah[2], al[2], bh[4], bl[4];
#pragma unroll
            for (int i = 0; i < 2; ++i) {
                ah[i] = *(const short8*)&sA[0][rb + i * 16 + lrow][ko];
                al[i] = *(const short8*)&sA[1][rb + i * 16 + lrow][ko];
            }
#pragma unroll
            for (int j = 0; j < 4; ++j) {
                bh[j] = *(const short8*)&sB[0][j * 16 + lrow][ko];
                bl[j] = *(const short8*)&sB[1][j * 16 + lrow][ko];
            }
#pragma unroll
            for (int i = 0; i < 2; ++i)
#pragma unroll
                for (int j = 0; j < 4; ++j) {
                    acc[i][j] = __builtin_amdgcn_mfma_f32_16x16x32_bf16(
                        ah[i], bh[j], acc[i][j], 0, 0, 0);
                    acc[i][j] = __builtin_amdgcn_mfma_f32_16x16x32_bf16(
                        ah[i], bl[j], acc[i][j], 0, 0, 0);
                    acc[i][j] = __builtin_amdgcn_mfma_f32_16x16x32_bf16(
                        al[i], bh[j], acc[i][j], 0, 0, 0);
                }
        }
        __syncthreads();
    }
    float sj[4] = {0.f, 0.f, 0.f, 0.f};
    float qj[4] = {0.f, 0.f, 0.f, 0.f};
#pragma unroll
    for (int i = 0; i < 2; ++i)
#pragma unroll
        for (int j = 0; j < 4; ++j) {
            int gc = bn + j * 16 + lrow;
            float bv = bias[gc];
#pragma unroll
            for (int r = 0; r < 4; ++r) {
                int gr = bm + wave * 32 + i * 16 + lquad * 4 + r;
                float v = acc[i][j][r] + bv;
                if (relu) v = fmaxf(v, 0.f);
                if (STATS && gr < Nreal) {
                    sj[j] += v;
                    qj[j] = fmaf(v, v, qj[j]);
                }
                if (WRITE_BF16) {
                    ushort hv = f2bf_rne(v);
                    ushort lv = f2bf_rne(v - bf2f(hv));
                    Chi[(size_t)gr * N + gc] = hv;
                    Clo[(size_t)gr * N + gc] = lv;
                } else {
                    Cf[(size_t)gr * N + gc] = v;
                }
            }
        }
    if (STATS) {
#pragma unroll
        for (int j = 0; j < 4; ++j) {
            float s = sj[j], q = qj[j];
            s += __shfl_xor(s, 16);
            s += __shfl_xor(s, 32);
            q += __shfl_xor(q, 16);
            q += __shfl_xor(q, 32);
            if (lquad == 0) {
                int gc = bn + j * 16 + lrow;
                atomicAdd(&stats[gc], s);
                atomicAdd(&stats[N + gc], q);
            }
        }
    }
}

// ---------------- BatchNorm apply (vectorized, + bf16 copy) ----------------
__global__ __launch_bounds__(256) void bn_apply_kernel(
    const float* __restrict__ r, float* __restrict__ h,
    ushort* __restrict__ hbout,
    const float* __restrict__ sums,
    const float* __restrict__ g, const float* __restrict__ bt,
    int N, int D, int Dm1) {
    int idx = blockIdx.x * blockDim.x + threadIdx.x;
    int total4 = N * D / 4;
    int stride = gridDim.x * blockDim.x;
    float invN = 1.0f / (float)N;
    for (; idx < total4; idx += stride) {
        int c = (idx * 4) & Dm1;
        float4 s4 = *(const float4*)&sums[c];
        float4 q4 = *(const float4*)&sums[D + c];
        float4 g4 = *(const float4*)&g[c];
        float4 b4 = *(const float4*)&bt[c];
        float4 r4 = ((const float4*)r)[idx];
        float4 o;
        {
            float mu = s4.x * invN;
            float var = fmaf(-mu, mu, q4.x * invN);
            o.x = (r4.x - mu) * (rsqrtf(var + 1e-5f) * g4.x) + b4.x;
            mu = s4.y * invN;
            var = fmaf(-mu, mu, q4.y * invN);
            o.y = (r4.y - mu) * (rsqrtf(var + 1e-5f) * g4.y) + b4.y;
            mu = s4.z * invN;
            var = fmaf(-mu, mu, q4.z * invN);
            o.z = (r4.z - mu) * (rsqrtf(var + 1e-5f) * g4.z) + b4.z;
            mu = s4.w * invN;
            var = fmaf(-mu, mu, q4.w * invN);
            o.w = (r4.w - mu) * (rsqrtf(var + 1e-5f) * g4.w) + b4.w;
        }
        ((float4*)h)[idx] = o;
        if (hbout) {
            ushort4 ob;
            ob.x = f2bf_rne(o.x);
            ob.y = f2bf_rne(o.y);
            ob.z = f2bf_rne(o.z);
            ob.w = f2bf_rne(o.w);
            ((ushort4*)hbout)[idx] = ob;
        }
    }
}

// ---------------- Head ----------------
__global__ void head_kernel(const float* __restrict__ h, const int* __restrict__ n_nodes,
                            const float* __restrict__ Wf1, const float* __restrict__ bf1,
                            const float* __restrict__ Wf2, const float* __restrict__ bf2,
                            float* __restrict__ out, int G) {
    int g = blockIdx.x * blockDim.x + threadIdx.x;
    if (g >= G) return;
    int s = 0;
    for (int i = 0; i <= g; ++i) s += n_nodes[i];
    const float* m = &h[(size_t)(s - 1) * 64];
    float o = bf2[0];
#pragma unroll 4
    for (int j = 0; j < 16; ++j) {
        float acc = bf1[j];
        for (int k = 0; k < 64; ++k) acc = fmaf(m[k], Wf1[k * 16 + j], acc);
        acc = fmaxf(acc, 0.f);
        o = fmaf(acc, Wf2[j], o);
    }
    out[g] = o;
}

extern "C" void kernel_launch(void* const* d_in, const int* in_sizes, int n_in,
                              void* d_out, int out_size, void* d_ws, size_t ws_size,
                              hipStream_t stream) {
    const float* x = (const float*)d_in[0];
    const float* ea = (const float*)d_in[1];
    const int* eidx = (const int*)d_in[2];
    const int* n_nodes = (const int*)d_in[3];
    const float* We1 = (const float*)d_in[4];
    const float* be1 = (const float*)d_in[5];
    const float* W11 = (const float*)d_in[6];
    const float* b11 = (const float*)d_in[7];
    const float* W12 = (const float*)d_in[8];
    const float* b12 = (const float*)d_in[9];
    const float* g1 = (const float*)d_in[10];
    const float* bt1 = (const float*)d_in[11];
    const float* We2 = (const float*)d_in[12];
    const float* be2 = (const float*)d_in[13];
    const float* W21 = (const float*)d_in[14];
    const float* b21 = (const float*)d_in[15];
    const float* W22 = (const float*)d_in[16];
    const float* b22 = (const float*)d_in[17];
    const float* g2 = (const float*)d_in[18];
    const float* bt2 = (const float*)d_in[19];
    const float* We3 = (const float*)d_in[20];
    const float* be3 = (const float*)d_in[21];
    const float* W31 = (const float*)d_in[22];
    const float* b31 = (const float*)d_in[23];
    const float* W32 = (const float*)d_in[24];
    const float* b32 = (const float*)d_in[25];
    const float* g3 = (const float*)d_in[26];
    const float* bt3 = (const float*)d_in[27];
    const float* Wf1 = (const float*)d_in[28];
    const float* bf1 = (const float*)d_in[29];
    const float* Wf2 = (const float*)d_in[30];
    const float* bf2 = (const float*)d_in[31];

    const int N = in_sizes[0] / 128;  // 50000
    const int E = in_sizes[2] / 2;    // 800000
    const int G = in_sizes[3];        // 500
    const int Mp = ((N + 127) / 128) * 128;  // 50048
    const int* srcp = eidx;
    const int* dstp = eidx + E;

    float* H = (float*)d_ws;            // Mp x 256 fp32
    float* UR = H + (size_t)Mp * 256;   // Mp x 256: u(hi/lo bf16) / r(fp32)
    float* TT = UR + (size_t)Mp * 256;  // Mp x 256: t(hi/lo bf16) / hb(bf16)
    float* stats1 = TT + (size_t)Mp * 256;  // 512
    float* stats2 = stats1 + 512;           // 256
    float* stats3 = stats2 + 256;           // 128
    int* deg = (int*)(stats3 + 128);        // N
    int* cursor = deg + N;                  // N
    int* row_start = cursor + N;            // N+1 (+1 pad for int2 align)
    int2* csr = (int2*)(row_start + N + 2); // E int2
    size_t woff = (size_t)((int*)(csr + E) - (int*)d_ws);
    woff = (woff + 3) & ~(size_t)3;
    ushort* wp = (ushort*)((int*)d_ws + woff);
    ushort* W11th = wp; wp += 128 * 256;
    ushort* W11tl = wp; wp += 128 * 256;
    ushort* W12th = wp; wp += 256 * 256;
    ushort* W12tl = wp; wp += 256 * 256;
    ushort* W21th = wp; wp += 256 * 128;
    ushort* W21tl = wp; wp += 256 * 128;
    ushort* W22th = wp; wp += 128 * 128;
    ushort* W22tl = wp; wp += 128 * 128;
    ushort* W31th = wp; wp += 128 * 64;
    ushort* W31tl = wp; wp += 128 * 64;
    ushort* W32th = wp; wp += 64 * 64;
    ushort* W32tl = wp; wp += 64 * 64;
    ushort* WeA1 = wp; wp += 8 * 512;    // edge-We MFMA A-frags L1
    ushort* WeA2 = wp; wp += 16 * 512;   // L2
    ushort* WeA3 = wp; wp += 8 * 512;    // L3
    // align eab to 16B
    {
        size_t off = (size_t)(wp - (ushort*)d_ws);
        off = (off + 7) & ~(size_t)7;
        wp = (ushort*)d_ws + off;
    }
    ushort* eab = wp;  // E x 32 bf16 (hi16|lo16) = 51.2 MB

    hipMemsetAsync(stats1, 0, 896 * sizeof(float) + (size_t)2 * N * sizeof(int), stream);

    const int prepTot = 128 * 256 + 256 * 256 + 256 * 128 + 128 * 128 + 128 * 64 + 64 * 64;
    prep_all<<<(prepTot + 255) / 256, 256, 0, stream>>>(
        W11, W11th, W11tl, W12, W12th, W12tl, W21, W21th, W21tl,
        W22, W22th, W22tl, W31, W31th, W31tl, W32, W32th, W32tl);
    prep_edgeWA<<<(32 * 512 + 255) / 256, 256, 0, stream>>>(
        We1, WeA1, We2, WeA2, We3, WeA3);
    prep_eab<<<3125, 256, 0, stream>>>(ea, eab, E);

    hist_kernel<<<3125, 256, 0, stream>>>(dstp, deg, E);
    scan_kernel<<<1, 1024, 0, stream>>>(deg, row_start, N);
    scatter_kernel<<<3125, 256, 0, stream>>>(srcp, dstp, row_start, cursor, csr, E);

    const int gy = Mp / 128;
    float* R = UR;
    ushort* HB = (ushort*)TT;  // bf16 gather copy lives in the (dead) TT region

    // ---------------- Layer 1: 128 -> 256 -> 256 ----------------
    {
        ushort* Uhi = (ushort*)UR; ushort* Ulo = Uhi + (size_t)Mp * 128;
        ushort* Thi = (ushort*)TT; ushort* Tlo = Thi + (size_t)Mp * 256;
        f32_to_bf16<<<2048, 256, 0, stream>>>(x, HB, (long)N * 128 / 4);
        gine_agg_mfma<128, 2><<<(N + 1) / 2, 256, 0, stream>>>(
            x, HB, eab, row_start, csr, WeA1, be1, Uhi, Ulo, N);
        gemm_mfma<1, 0><<<dim3(4, gy), 256, 0, stream>>>(
            Uhi, Ulo, W11th, W11tl, b11, nullptr, Thi, Tlo, nullptr, 0, 256, 128, 1);
        gemm_mfma<0, 1><<<dim3(4, gy), 256, 0, stream>>>(
            Thi, Tlo, W12th, W12tl, b12, R, nullptr, nullptr, stats1, N, 256, 256, 1);
        bn_apply_kernel<<<2048, 256, 0, stream>>>(R, H, HB, stats1, g1, bt1, N, 256, 255);
    }

    // ---------------- Layer 2: 256 -> 128 -> 128 ----------------
    {
        ushort* Uhi = (ushort*)UR; ushort* Ulo = Uhi + (size_t)Mp * 256;
        ushort* Thi = (ushort*)TT; ushort* Tlo = Thi + (size_t)Mp * 128;
        gine_agg_mfma<256, 4><<<N, 256, 0, stream>>>(
            H, HB, eab, row_start, csr, WeA2, be2, Uhi, Ulo, N);
        gemm_mfma<1, 0><<<dim3(2, gy), 256, 0, stream>>>(
            Uhi, Ulo, W21th, W21tl, b21, nullptr, Thi, Tlo, nullptr, 0, 128, 256, 1);
        gemm_mfma<0, 1><<<dim3(2, gy), 256, 0, stream>>>(
            Thi, Tlo, W22th, W22tl, b22, R, nullptr, nullptr, stats2, N, 128, 128, 1);
        bn_apply_kernel<<<2048, 256, 0, stream>>>(R, H, HB, stats2, g2, bt2, N, 128, 127);
    }

    // ---------------- Layer 3: 128 -> 64 -> 64 ----------------
    {
        ushort* Uhi = (ushort*)UR; ushort* Ulo = Uhi + (size_t)Mp * 128;
        ushort* Thi = (ushort*)TT; ushort* Tlo = Thi + (size_t)Mp * 64;
        gine_agg_mfma<128, 2><<<(N + 1) / 2, 256, 0, stream>>>(
            H, HB, eab, row_start, csr, WeA3, be3, Uhi, Ulo, N);
        gemm_mfma<1, 0><<<dim3(1, gy), 256, 0, stream>>>(
            Uhi, Ulo, W31th, W31tl, b31, nullptr, Thi, Tlo, nullptr, 0, 64, 128, 1);
        gemm_mfma<0, 1><<<dim3(1, gy), 256, 0, stream>>>(
            Thi, Tlo, W32th, W32tl, b32, R, nullptr, nullptr, stats3, N, 64, 64, 1);
        bn_apply_kernel<<<2048, 256, 0, stream>>>(R, H, nullptr, stats3, g3, bt3, N, 64, 63);
    }

    // ---------------- Head ----------------
    head_kernel<<<(G + 255) / 256, 256, 0, stream>>>(H, n_nodes, Wf1, bf1, Wf2, bf2,
                                                     (float*)d_out, G);
}

// Round 4
// 1294.194 us; speedup vs baseline: 1.0290x; 1.0054x over previous
//
#include <hip/hip_runtime.h>
#include <hip/hip_bf16.h>

// ---------------------------------------------------------------------------
// GIN0 (GINE x3 + BN + head) forward.
// R1: CSR + per-node register aggregation (no atomics in hot path).
// R3: node MLP GEMMs on MFMA via split-bf16 (hi+lo, 3-pass).
// R5: BN stats fused into GEMM2 epilogue; single prep kernel.
// R6: gathers read a bf16 copy of h; self-term fp32.
// R8: WPN waves/node so We slice stays VGPR-resident.
// R13: (MFMA agg abandoned after R11/R12 — per-edge relu forces per-body
//      C extraction + butterfly; latency-bound at 4.9% MfmaUtil.)
//      Back to pk_fma agg with the R10 stall source removed:
//      - ea materialized in CSR order (eacsr, fp32 64B/edge, one prep pass)
//        -> inner loop reads ea SEQUENTIALLY, zero indirection/readlanes.
//      - uniform VMEM loads (1 transaction, vmcnt fine-waitable) feed
//        v_pk_fma_f32 via VGPR-pair + op_sel dword broadcast.
//      - unroll-2 A/B software pipeline, src prefetched 2 edges ahead,
//        gather 1 edge ahead; single-edge granularity (no tail masking).
// ---------------------------------------------------------------------------

typedef __attribute__((ext_vector_type(8))) short short8;
typedef __attribute__((ext_vector_type(4))) float floatx4;
typedef __attribute__((ext_vector_type(2))) float float2v;
typedef unsigned long long u64;

// p += bcast(lo dword of e) * w   (packed fp32, VGPR-pair scalar operand)
__device__ __forceinline__ float2v pkfma_lo(u64 e, float2v w, float2v p) {
    asm("v_pk_fma_f32 %0, %1, %2, %0 op_sel:[0,0,0] op_sel_hi:[0,1,1]"
        : "+v"(p) : "v"(e), "v"(w));
    return p;
}

// p += bcast(hi dword of e) * w
__device__ __forceinline__ float2v pkfma_hi(u64 e, float2v w, float2v p) {
    asm("v_pk_fma_f32 %0, %1, %2, %0 op_sel:[1,0,0] op_sel_hi:[1,1,1]"
        : "+v"(p) : "v"(e), "v"(w));
    return p;
}

__device__ __forceinline__ ushort f2bf_rne(float x) {
    unsigned u = __float_as_uint(x);
    unsigned r = (u + 0x7FFFu + ((u >> 16) & 1u)) >> 16;
    return (ushort)r;
}

__device__ __forceinline__ float bf2f(ushort u) {
    return __uint_as_float(((unsigned)u) << 16);
}

// ---------------- CSR build ----------------

__global__ __launch_bounds__(256) void hist_kernel(const int* __restrict__ dst,
                                                   int* __restrict__ deg, int E) {
    int i = blockIdx.x * blockDim.x + threadIdx.x;
    int stride = gridDim.x * blockDim.x;
    for (; i < E; i += stride) atomicAdd(&deg[dst[i]], 1);
}

__global__ __launch_bounds__(1024) void scan_kernel(const int* __restrict__ deg,
                                                    int* __restrict__ row_start, int N) {
    __shared__ int part[1024];
    int tid = threadIdx.x;
    int per = (N + 1023) / 1024;
    int start = tid * per;
    int end = min(start + per, N);
    int s = 0;
    for (int i = start; i < end; ++i) s += deg[i];
    part[tid] = s;
    __syncthreads();
    if (tid == 0) {
        int t = 0;
        for (int i = 0; i < 1024; ++i) {
            int v = part[i];
            part[i] = t;
            t += v;
        }
    }
    __syncthreads();
    int run = part[tid];
    for (int i = start; i < end; ++i) {
        row_start[i] = run;
        run += deg[i];
    }
    if (tid == 1023) row_start[N] = run;
}

__global__ __launch_bounds__(256) void scatter_kernel(
    const int* __restrict__ src, const int* __restrict__ dst,
    const int* __restrict__ row_start, int* __restrict__ cursor,
    int* __restrict__ ceid, int* __restrict__ csrc, int E) {
    int i = blockIdx.x * blockDim.x + threadIdx.x;
    int stride = gridDim.x * blockDim.x;
    for (; i < E; i += stride) {
        int v = dst[i];
        int p = row_start[v] + atomicAdd(&cursor[v], 1);
        ceid[p] = i;
        csrc[p] = src[i];
    }
}

// ---------------- ea -> CSR order (fp32 stream for the agg loop) ----------
__global__ __launch_bounds__(256) void eacsr_gather(const float* __restrict__ ea,
                                                    const int* __restrict__ ceid,
                                                    float* __restrict__ eacsr, long total) {
    long t = (long)blockIdx.x * 256 + threadIdx.x;
    long stride = (long)gridDim.x * 256;
    for (; t < total; t += stride) {
        long p = t >> 4;
        int c = (int)(t & 15);
        eacsr[t] = ea[(size_t)ceid[p] * 16 + c];
    }
}

// ---------------- Weight prep (node MLP GEMM weights) ----------------
__device__ __forceinline__ void wsplit(const float* W, ushort* Wth, ushort* Wtl,
                                       int K, int N, int t) {
    int k = t / N, n = t - k * N;
    float v = W[t];
    ushort hv = f2bf_rne(v);
    float hf = bf2f(hv);
    ushort lv = f2bf_rne(v - hf);
    Wth[(size_t)n * K + k] = hv;
    Wtl[(size_t)n * K + k] = lv;
}

__global__ __launch_bounds__(256) void prep_all(
    const float* W11, ushort* W11h, ushort* W11l,
    const float* W12, ushort* W12h, ushort* W12l,
    const float* W21, ushort* W21h, ushort* W21l,
    const float* W22, ushort* W22h, ushort* W22l,
    const float* W31, ushort* W31h, ushort* W31l,
    const float* W32, ushort* W32h, ushort* W32l) {
    int t = blockIdx.x * blockDim.x + threadIdx.x;
    const int s1 = 128 * 256, s2 = s1 + 256 * 256, s3 = s2 + 256 * 128;
    const int s4 = s3 + 128 * 128, s5 = s4 + 128 * 64, s6 = s5 + 64 * 64;
    if (t < s1) wsplit(W11, W11h, W11l, 128, 256, t);
    else if (t < s2) wsplit(W12, W12h, W12l, 256, 256, t - s1);
    else if (t < s3) wsplit(W21, W21h, W21l, 256, 128, t - s2);
    else if (t < s4) wsplit(W22, W22h, W22l, 128, 128, t - s3);
    else if (t < s5) wsplit(W31, W31h, W31l, 128, 64, t - s4);
    else if (t < s6) wsplit(W32, W32h, W32l, 64, 64, t - s5);
}

// ---------------- fp32 -> bf16 convert (layer-1 gather copy) --------------
__global__ __launch_bounds__(256) void f32_to_bf16(const float* __restrict__ in,
                                                   ushort* __restrict__ out, long n4) {
    long i = (long)blockIdx.x * blockDim.x + threadIdx.x;
    long stride = (long)gridDim.x * blockDim.x;
    for (; i < n4; i += stride) {
        float4 v = ((const float4*)in)[i];
        ushort4 o;
        o.x = f2bf_rne(v.x);
        o.y = f2bf_rne(v.y);
        o.z = f2bf_rne(v.z);
        o.w = f2bf_rne(v.w);
        ((ushort4*)out)[i] = o;
    }
}

// ---------------- Fused GINE aggregation ----------------
// Per edge: acc += relu(proj(ea) + x_src). ea read sequentially from eacsr
// via uniform VMEM loads (u64 pairs) feeding 16 pk_fma (op_sel broadcast).
// Software pipeline: A/B edge buffers, srcs prefetched 2 ahead.
template <int D, int WPN>
__global__ __launch_bounds__(256) void gine_agg_kernel(
    const float* __restrict__ h, const ushort* __restrict__ hb,
    const float* __restrict__ eacsr,
    const int* __restrict__ row_start, const int* __restrict__ csrc,
    const float* __restrict__ We, const float* __restrict__ be,
    ushort* __restrict__ uhi, ushort* __restrict__ ulo, int N) {
    constexpr int NPB = 4 / WPN;  // nodes per 256-thread block
    const int lane = threadIdx.x & 63;
    const int wid = threadIdx.x >> 6;
    const int ch0 = (wid % WPN) * 128 + lane * 2;

    float2v w[16];
#pragma unroll
    for (int k = 0; k < 16; ++k) w[k] = *(const float2v*)&We[k * D + ch0];
    const float2v bias = *(const float2v*)&be[ch0];

    const int v = blockIdx.x * NPB + wid / WPN;
    if (v >= N) return;
    float2v z2; z2[0] = 0.f; z2[1] = 0.f;

    const int e0 = row_start[v];
    const int e1 = row_start[v + 1];
    float2v acc = z2;

#define LOADEA(B0, B1, B2, B3, B4, B5, B6, B7, idx)                  \
    {                                                                \
        const u64* q_ = (const u64*)eacsr + (size_t)(idx) * 8;       \
        B0 = q_[0]; B1 = q_[1]; B2 = q_[2]; B3 = q_[3];              \
        B4 = q_[4]; B5 = q_[5]; B6 = q_[6]; B7 = q_[7];              \
    }

#define COMP(B0, B1, B2, B3, B4, B5, B6, B7, r)                      \
    {                                                                \
        float2v p = bias;                                            \
        p = pkfma_lo(B0, w[0], p);  p = pkfma_hi(B0, w[1], p);       \
        p = pkfma_lo(B1, w[2], p);  p = pkfma_hi(B1, w[3], p);       \
        p = pkfma_lo(B2, w[4], p);  p = pkfma_hi(B2, w[5], p);       \
        p = pkfma_lo(B3, w[6], p);  p = pkfma_hi(B3, w[7], p);       \
        p = pkfma_lo(B4, w[8], p);  p = pkfma_hi(B4, w[9], p);       \
        p = pkfma_lo(B5, w[10], p); p = pkfma_hi(B5, w[11], p);      \
        p = pkfma_lo(B6, w[12], p); p = pkfma_hi(B6, w[13], p);      \
        float2v hv;                                                  \
        hv[0] = __uint_as_float((r) << 16);                          \
        hv[1] = __uint_as_float((r) & 0xffff0000u);                  \
        p = pkfma_lo(B7, w[14], p); p = pkfma_hi(B7, w[15], p);      \
        float2v m = p + hv;                                          \
        acc += __builtin_elementwise_max(m, z2);                     \
    }

    if (e1 > e0) {
        int i = e0;
        u64 A0, A1, A2, A3, A4, A5, A6, A7;
        u64 B0, B1, B2, B3, B4, B5, B6, B7;
        int s0 = csrc[i];
        LOADEA(A0, A1, A2, A3, A4, A5, A6, A7, i);
        unsigned rA = *(const unsigned*)&hb[(size_t)s0 * D + ch0];
        int s1 = csrc[i + 1];  // pad-safe (csrc has +2 pad)
        while (i + 2 < e1) {
            LOADEA(B0, B1, B2, B3, B4, B5, B6, B7, i + 1);
            unsigned rB = *(const unsigned*)&hb[(size_t)s1 * D + ch0];
            int s2 = csrc[i + 2];
            COMP(A0, A1, A2, A3, A4, A5, A6, A7, rA);  // edge i
            LOADEA(A0, A1, A2, A3, A4, A5, A6, A7, i + 2);
            rA = *(const unsigned*)&hb[(size_t)s2 * D + ch0];
            s1 = csrc[i + 3];  // pad-safe
            COMP(B0, B1, B2, B3, B4, B5, B6, B7, rB);  // edge i+1
            i += 2;
        }
        COMP(A0, A1, A2, A3, A4, A5, A6, A7, rA);  // edge i
        if (i + 1 < e1) {
            LOADEA(B0, B1, B2, B3, B4, B5, B6, B7, i + 1);
            unsigned rB = *(const unsigned*)&hb[(size_t)s1 * D + ch0];
            COMP(B0, B1, B2, B3, B4, B5, B6, B7, rB);
        }
    }
#undef LOADEA
#undef COMP

    // epilogue: u = h_v + acc -> bf16 hi/lo
    float2v sv = *(const float2v*)&h[(size_t)v * D + ch0];
    float u0 = sv[0] + acc[0];
    float u1 = sv[1] + acc[1];
    ushort h0 = f2bf_rne(u0);
    ushort h1 = f2bf_rne(u1);
    ushort l0 = f2bf_rne(u0 - bf2f(h0));
    ushort l1 = f2bf_rne(u1 - bf2f(h1));
    *(ushort2*)&uhi[(size_t)v * D + ch0] = make_ushort2(h0, h1);
    *(ushort2*)&ulo[(size_t)v * D + ch0] = make_ushort2(l0, l1);
}

// ---------------- Split-bf16 MFMA GEMM (+ optional fused BN stats) ---------
template <int WRITE_BF16, int STATS>
__global__ __launch_bounds__(256) void gemm_mfma(
    const ushort* __restrict__ Ah, const ushort* __restrict__ Al,
    const ushort* __restrict__ Bh, const ushort* __restrict__ Bl,
    const float* __restrict__ bias,
    float* __restrict__ Cf, ushort* __restrict__ Chi, ushort* __restrict__ Clo,
    float* __restrict__ stats, int Nreal,
    int N, int K, int relu) {
    __shared__ ushort sA[2][128][72];
    __shared__ ushort sB[2][64][72];
    const int tid = threadIdx.x;
    const int wave = tid >> 6, lane = tid & 63;
    const int lrow = lane & 15, lquad = lane >> 4;
    const int bm = blockIdx.y * 128;
    const int bn = blockIdx.x * 64;

    floatx4 acc[2][4];
#pragma unroll
    for (int i = 0; i < 2; ++i)
#pragma unroll
        for (int j = 0; j < 4; ++j) acc[i][j] = (floatx4)0.f;

    for (int k0 = 0; k0 < K; k0 += 64) {
        for (int s = tid; s < 1024; s += 256) {
            int row = s >> 3, c8 = (s & 7) * 8;
            size_t g = (size_t)(bm + row) * K + k0 + c8;
            *(int4*)&sA[0][row][c8] = *(const int4*)&Ah[g];
            *(int4*)&sA[1][row][c8] = *(const int4*)&Al[g];
        }
        for (int s = tid; s < 512; s += 256) {
            int row = s >> 3, c8 = (s & 7) * 8;
            size_t g = (size_t)(bn + row) * K + k0 + c8;
            *(int4*)&sB[0][row][c8] = *(const int4*)&Bh[g];
            *(int4*)&sB[1][row][c8] = *(const int4*)&Bl[g];
        }
        __syncthreads();
        const int rb = wave * 32;
#pragma unroll
        for (int kk = 0; kk < 2; ++kk) {
            int ko = kk * 32 + lquad * 8;
            short8 ah[2], al[2], bh[4], bl[4];
#pragma unroll
            for (int i = 0; i < 2; ++i) {
                ah[i] = *(const short8*)&sA[0][rb + i * 16 + lrow][ko];
                al[i] = *(const short8*)&sA[1][rb + i * 16 + lrow][ko];
            }
#pragma unroll
            for (int j = 0; j < 4; ++j) {
                bh[j] = *(const short8*)&sB[0][j * 16 + lrow][ko];
                bl[j] = *(const short8*)&sB[1][j * 16 + lrow][ko];
            }
#pragma unroll
            for (int i = 0; i < 2; ++i)
#pragma unroll
                for (int j = 0; j < 4; ++j) {
                    acc[i][j] = __builtin_amdgcn_mfma_f32_16x16x32_bf16(
                        ah[i], bh[j], acc[i][j], 0, 0, 0);
                    acc[i][j] = __builtin_amdgcn_mfma_f32_16x16x32_bf16(
                        ah[i], bl[j], acc[i][j], 0, 0, 0);
                    acc[i][j] = __builtin_amdgcn_mfma_f32_16x16x32_bf16(
                        al[i], bh[j], acc[i][j], 0, 0, 0);
                }
        }
        __syncthreads();
    }
    float sj[4] = {0.f, 0.f, 0.f, 0.f};
    float qj[4] = {0.f, 0.f, 0.f, 0.f};
#pragma unroll
    for (int i = 0; i < 2; ++i)
#pragma unroll
        for (int j = 0; j < 4; ++j) {
            int gc = bn + j * 16 + lrow;
            float bv = bias[gc];
#pragma unroll
            for (int r = 0; r < 4; ++r) {
                int gr = bm + wave * 32 + i * 16 + lquad * 4 + r;
                float v = acc[i][j][r] + bv;
                if (relu) v = fmaxf(v, 0.f);
                if (STATS && gr < Nreal) {
                    sj[j] += v;
                    qj[j] = fmaf(v, v, qj[j]);
                }
                if (WRITE_BF16) {
                    ushort hv = f2bf_rne(v);
                    ushort lv = f2bf_rne(v - bf2f(hv));
                    Chi[(size_t)gr * N + gc] = hv;
                    Clo[(size_t)gr * N + gc] = lv;
                } else {
                    Cf[(size_t)gr * N + gc] = v;
                }
            }
        }
    if (STATS) {
#pragma unroll
        for (int j = 0; j < 4; ++j) {
            float s = sj[j], q = qj[j];
            s += __shfl_xor(s, 16);
            s += __shfl_xor(s, 32);
            q += __shfl_xor(q, 16);
            q += __shfl_xor(q, 32);
            if (lquad == 0) {
                int gc = bn + j * 16 + lrow;
                atomicAdd(&stats[gc], s);
                atomicAdd(&stats[N + gc], q);
            }
        }
    }
}

// ---------------- BatchNorm apply (vectorized, + bf16 copy) ----------------
__global__ __launch_bounds__(256) void bn_apply_kernel(
    const float* __restrict__ r, float* __restrict__ h,
    ushort* __restrict__ hbout,
    const float* __restrict__ sums,
    const float* __restrict__ g, const float* __restrict__ bt,
    int N, int D, int Dm1) {
    int idx = blockIdx.x * blockDim.x + threadIdx.x;
    int total4 = N * D / 4;
    int stride = gridDim.x * blockDim.x;
    float invN = 1.0f / (float)N;
    for (; idx < total4; idx += stride) {
        int c = (idx * 4) & Dm1;
        float4 s4 = *(const float4*)&sums[c];
        float4 q4 = *(const float4*)&sums[D + c];
        float4 g4 = *(const float4*)&g[c];
        float4 b4 = *(const float4*)&bt[c];
        float4 r4 = ((const float4*)r)[idx];
        float4 o;
        {
            float mu = s4.x * invN;
            float var = fmaf(-mu, mu, q4.x * invN);
            o.x = (r4.x - mu) * (rsqrtf(var + 1e-5f) * g4.x) + b4.x;
            mu = s4.y * invN;
            var = fmaf(-mu, mu, q4.y * invN);
            o.y = (r4.y - mu) * (rsqrtf(var + 1e-5f) * g4.y) + b4.y;
            mu = s4.z * invN;
            var = fmaf(-mu, mu, q4.z * invN);
            o.z = (r4.z - mu) * (rsqrtf(var + 1e-5f) * g4.z) + b4.z;
            mu = s4.w * invN;
            var = fmaf(-mu, mu, q4.w * invN);
            o.w = (r4.w - mu) * (rsqrtf(var + 1e-5f) * g4.w) + b4.w;
        }
        ((float4*)h)[idx] = o;
        if (hbout) {
            ushort4 ob;
            ob.x = f2bf_rne(o.x);
            ob.y = f2bf_rne(o.y);
            ob.z = f2bf_rne(o.z);
            ob.w = f2bf_rne(o.w);
            ((ushort4*)hbout)[idx] = ob;
        }
    }
}

// ---------------- Head ----------------
__global__ void head_kernel(const float* __restrict__ h, const int* __restrict__ n_nodes,
                            const float* __restrict__ Wf1, const float* __restrict__ bf1,
                            const float* __restrict__ Wf2, const float* __restrict__ bf2,
                            float* __restrict__ out, int G) {
    int g = blockIdx.x * blockDim.x + threadIdx.x;
    if (g >= G) return;
    int s = 0;
    for (int i = 0; i <= g; ++i) s += n_nodes[i];
    const float* m = &h[(size_t)(s - 1) * 64];
    float o = bf2[0];
#pragma unroll 4
    for (int j = 0; j < 16; ++j) {
        float acc = bf1[j];
        for (int k = 0; k < 64; ++k) acc = fmaf(m[k], Wf1[k * 16 + j], acc);
        acc = fmaxf(acc, 0.f);
        o = fmaf(acc, Wf2[j], o);
    }
    out[g] = o;
}

extern "C" void kernel_launch(void* const* d_in, const int* in_sizes, int n_in,
                              void* d_out, int out_size, void* d_ws, size_t ws_size,
                              hipStream_t stream) {
    const float* x = (const float*)d_in[0];
    const float* ea = (const float*)d_in[1];
    const int* eidx = (const int*)d_in[2];
    const int* n_nodes = (const int*)d_in[3];
    const float* We1 = (const float*)d_in[4];
    const float* be1 = (const float*)d_in[5];
    const float* W11 = (const float*)d_in[6];
    const float* b11 = (const float*)d_in[7];
    const float* W12 = (const float*)d_in[8];
    const float* b12 = (const float*)d_in[9];
    const float* g1 = (const float*)d_in[10];
    const float* bt1 = (const float*)d_in[11];
    const float* We2 = (const float*)d_in[12];
    const float* be2 = (const float*)d_in[13];
    const float* W21 = (const float*)d_in[14];
    const float* b21 = (const float*)d_in[15];
    const float* W22 = (const float*)d_in[16];
    const float* b22 = (const float*)d_in[17];
    const float* g2 = (const float*)d_in[18];
    const float* bt2 = (const float*)d_in[19];
    const float* We3 = (const float*)d_in[20];
    const float* be3 = (const float*)d_in[21];
    const float* W31 = (const float*)d_in[22];
    const float* b31 = (const float*)d_in[23];
    const float* W32 = (const float*)d_in[24];
    const float* b32 = (const float*)d_in[25];
    const float* g3 = (const float*)d_in[26];
    const float* bt3 = (const float*)d_in[27];
    const float* Wf1 = (const float*)d_in[28];
    const float* bf1 = (const float*)d_in[29];
    const float* Wf2 = (const float*)d_in[30];
    const float* bf2 = (const float*)d_in[31];

    const int N = in_sizes[0] / 128;  // 50000
    const int E = in_sizes[2] / 2;    // 800000
    const int G = in_sizes[3];        // 500
    const int Mp = ((N + 127) / 128) * 128;  // 50048
    const int* srcp = eidx;
    const int* dstp = eidx + E;

    float* H = (float*)d_ws;            // Mp x 256 fp32
    float* UR = H + (size_t)Mp * 256;   // Mp x 256: u(hi/lo bf16) / r(fp32)
    float* TT = UR + (size_t)Mp * 256;  // Mp x 256: t(hi/lo bf16) / hb(bf16)
    float* stats1 = TT + (size_t)Mp * 256;  // 512
    float* stats2 = stats1 + 512;           // 256
    float* stats3 = stats2 + 256;           // 128
    int* deg = (int*)(stats3 + 128);        // N
    int* cursor = deg + N;                  // N
    int* row_start = cursor + N;            // N+1 (+1 pad)
    int* ceid = row_start + N + 2;          // E
    int* csrc = ceid + E;                   // E (+2 pad)
    ushort* wp = (ushort*)(csrc + E + 2);
    ushort* W11th = wp; wp += 128 * 256;
    ushort* W11tl = wp; wp += 128 * 256;
    ushort* W12th = wp; wp += 256 * 256;
    ushort* W12tl = wp; wp += 256 * 256;
    ushort* W21th = wp; wp += 256 * 128;
    ushort* W21tl = wp; wp += 256 * 128;
    ushort* W22th = wp; wp += 128 * 128;
    ushort* W22tl = wp; wp += 128 * 128;
    ushort* W31th = wp; wp += 128 * 64;
    ushort* W31tl = wp; wp += 128 * 64;
    ushort* W32th = wp; wp += 64 * 64;
    ushort* W32tl = wp; wp += 64 * 64;
    // align to 16B for eacsr
    float* eacsr;
    {
        size_t off = (size_t)((char*)wp - (char*)d_ws);
        off = (off + 15) & ~(size_t)15;
        eacsr = (float*)((char*)d_ws + off);  // E x 16 fp32 = 51.2 MB
    }

    hipMemsetAsync(stats1, 0, 896 * sizeof(float) + (size_t)2 * N * sizeof(int), stream);

    const int prepTot = 128 * 256 + 256 * 256 + 256 * 128 + 128 * 128 + 128 * 64 + 64 * 64;
    prep_all<<<(prepTot + 255) / 256, 256, 0, stream>>>(
        W11, W11th, W11tl, W12, W12th, W12tl, W21, W21th, W21tl,
        W22, W22th, W22tl, W31, W31th, W31tl, W32, W32th, W32tl);

    hist_kernel<<<3125, 256, 0, stream>>>(dstp, deg, E);
    scan_kernel<<<1, 1024, 0, stream>>>(deg, row_start, N);
    scatter_kernel<<<3125, 256, 0, stream>>>(srcp, dstp, row_start, cursor, ceid, csrc, E);
    eacsr_gather<<<12500, 256, 0, stream>>>(ea, ceid, eacsr, (long)E * 16);

    const int gy = Mp / 128;
    float* R = UR;
    ushort* HB = (ushort*)TT;  // bf16 gather copy lives in the (dead) TT region

    // ---------------- Layer 1: 128 -> 256 -> 256 ----------------
    {
        ushort* Uhi = (ushort*)UR; ushort* Ulo = Uhi + (size_t)Mp * 128;
        ushort* Thi = (ushort*)TT; ushort* Tlo = Thi + (size_t)Mp * 256;
        f32_to_bf16<<<2048, 256, 0, stream>>>(x, HB, (long)N * 128 / 4);
        gine_agg_kernel<128, 1><<<(N + 3) / 4, 256, 0, stream>>>(
            x, HB, eacsr, row_start, csrc, We1, be1, Uhi, Ulo, N);
        gemm_mfma<1, 0><<<dim3(4, gy), 256, 0, stream>>>(
            Uhi, Ulo, W11th, W11tl, b11, nullptr, Thi, Tlo, nullptr, 0, 256, 128, 1);
        gemm_mfma<0, 1><<<dim3(4, gy), 256, 0, stream>>>(
            Thi, Tlo, W12th, W12tl, b12, R, nullptr, nullptr, stats1, N, 256, 256, 1);
        bn_apply_kernel<<<2048, 256, 0, stream>>>(R, H, HB, stats1, g1, bt1, N, 256, 255);
    }

    // ---------------- Layer 2: 256 -> 128 -> 128 ----------------
    {
        ushort* Uhi = (ushort*)UR; ushort* Ulo = Uhi + (size_t)Mp * 256;
        ushort* Thi = (ushort*)TT; ushort* Tlo = Thi + (size_t)Mp * 128;
        gine_agg_kernel<256, 2><<<(N + 1) / 2, 256, 0, stream>>>(
            H, HB, eacsr, row_start, csrc, We2, be2, Uhi, Ulo, N);
        gemm_mfma<1, 0><<<dim3(2, gy), 256, 0, stream>>>(
            Uhi, Ulo, W21th, W21tl, b21, nullptr, Thi, Tlo, nullptr, 0, 128, 256, 1);
        gemm_mfma<0, 1><<<dim3(2, gy), 256, 0, stream>>>(
            Thi, Tlo, W22th, W22tl, b22, R, nullptr, nullptr, stats2, N, 128, 128, 1);
        bn_apply_kernel<<<2048, 256, 0, stream>>>(R, H, HB, stats2, g2, bt2, N, 128, 127);
    }

    // ---------------- Layer 3: 128 -> 64 -> 64 ----------------
    {
        ushort* Uhi = (ushort*)UR; ushort* Ulo = Uhi + (size_t)Mp * 128;
        ushort* Thi = (ushort*)TT; ushort* Tlo = Thi + (size_t)Mp * 64;
        gine_agg_kernel<128, 1><<<(N + 3) / 4, 256, 0, stream>>>(
            H, HB, eacsr, row_start, csrc, We3, be3, Uhi, Ulo, N);
        gemm_mfma<1, 0><<<dim3(1, gy), 256, 0, stream>>>(
            Uhi, Ulo, W31th, W31tl, b31, nullptr, Thi, Tlo, nullptr, 0, 64, 128, 1);
        gemm_mfma<0, 1><<<dim3(1, gy), 256, 0, stream>>>(
            Thi, Tlo, W32th, W32tl, b32, R, nullptr, nullptr, stats3, N, 64, 64, 1);
        bn_apply_kernel<<<2048, 256, 0, stream>>>(R, H, nullptr, stats3, g3, bt3, N, 64, 63);
    }

    // ---------------- Head ----------------
    head_kernel<<<(G + 255) / 256, 256, 0, stream>>>(H, n_nodes, Wf1, bf1, Wf2, bf2,
                                                     (float*)d_out, G);
}

// Round 5
// 969.276 us; speedup vs baseline: 1.3740x; 1.3352x over previous
//
#include <hip/hip_runtime.h>
#include <hip/hip_bf16.h>

// ---------------------------------------------------------------------------
// GIN0 (GINE x3 + BN + head) forward.
// R1: CSR + per-node register aggregation (no atomics in hot path).
// R3: node MLP GEMMs on MFMA via split-bf16 (hi+lo, 3-pass).
// R5: BN stats fused into GEMM2 epilogue; single prep kernel.
// R6: gathers read a bf16 copy of h; self-term fp32.
// R8: WPN waves/node so We slice stays VGPR-resident.
// R14: agg = R10 structure (4-edge blocks, batched gathers, pk_fma w/
//      op_sel broadcast) + eacsr (ea materialized in CSR order, R13) +
//      airtight scalarization: i = readfirstlane(row_start[v]) makes all
//      ea addresses SGPR-born -> merged s_load_dwordx16, 1 SMEM instr per
//      edge, sequential. No readlane storms, no per-lane ea broadcasts.
// ---------------------------------------------------------------------------

typedef __attribute__((ext_vector_type(8))) short short8;
typedef __attribute__((ext_vector_type(4))) float floatx4;
typedef __attribute__((ext_vector_type(2))) float float2v;
typedef unsigned long long u64;

// p += bcast(lo dword of e) * w   (packed fp32, SGPR-pair scalar operand)
__device__ __forceinline__ float2v pkfma_lo(u64 e, float2v w, float2v p) {
    asm("v_pk_fma_f32 %0, %1, %2, %0 op_sel:[0,0,0] op_sel_hi:[0,1,1]"
        : "+v"(p) : "s"(e), "v"(w));
    return p;
}

// p += bcast(hi dword of e) * w
__device__ __forceinline__ float2v pkfma_hi(u64 e, float2v w, float2v p) {
    asm("v_pk_fma_f32 %0, %1, %2, %0 op_sel:[1,0,0] op_sel_hi:[1,1,1]"
        : "+v"(p) : "s"(e), "v"(w));
    return p;
}

__device__ __forceinline__ ushort f2bf_rne(float x) {
    unsigned u = __float_as_uint(x);
    unsigned r = (u + 0x7FFFu + ((u >> 16) & 1u)) >> 16;
    return (ushort)r;
}

__device__ __forceinline__ float bf2f(ushort u) {
    return __uint_as_float(((unsigned)u) << 16);
}

// ---------------- CSR build ----------------

__global__ __launch_bounds__(256) void hist_kernel(const int* __restrict__ dst,
                                                   int* __restrict__ deg, int E) {
    int i = blockIdx.x * blockDim.x + threadIdx.x;
    int stride = gridDim.x * blockDim.x;
    for (; i < E; i += stride) atomicAdd(&deg[dst[i]], 1);
}

__global__ __launch_bounds__(1024) void scan_kernel(const int* __restrict__ deg,
                                                    int* __restrict__ row_start, int N) {
    __shared__ int part[1024];
    int tid = threadIdx.x;
    int per = (N + 1023) / 1024;
    int start = tid * per;
    int end = min(start + per, N);
    int s = 0;
    for (int i = start; i < end; ++i) s += deg[i];
    part[tid] = s;
    __syncthreads();
    if (tid == 0) {
        int t = 0;
        for (int i = 0; i < 1024; ++i) {
            int v = part[i];
            part[i] = t;
            t += v;
        }
    }
    __syncthreads();
    int run = part[tid];
    for (int i = start; i < end; ++i) {
        row_start[i] = run;
        run += deg[i];
    }
    if (tid == 1023) row_start[N] = run;
}

__global__ __launch_bounds__(256) void scatter_kernel(
    const int* __restrict__ src, const int* __restrict__ dst,
    const int* __restrict__ row_start, int* __restrict__ cursor,
    int* __restrict__ ceid, int* __restrict__ csrc, int E) {
    int i = blockIdx.x * blockDim.x + threadIdx.x;
    int stride = gridDim.x * blockDim.x;
    for (; i < E; i += stride) {
        int v = dst[i];
        int p = row_start[v] + atomicAdd(&cursor[v], 1);
        ceid[p] = i;
        csrc[p] = src[i];
    }
}

// ---------------- ea -> CSR order (fp32 stream for the agg loop) ----------
__global__ __launch_bounds__(256) void eacsr_gather(const float* __restrict__ ea,
                                                    const int* __restrict__ ceid,
                                                    float* __restrict__ eacsr, long total) {
    long t = (long)blockIdx.x * 256 + threadIdx.x;
    long stride = (long)gridDim.x * 256;
    for (; t < total; t += stride) {
        long p = t >> 4;
        int c = (int)(t & 15);
        eacsr[t] = ea[(size_t)ceid[p] * 16 + c];
    }
}

// ---------------- Weight prep (node MLP GEMM weights) ----------------
__device__ __forceinline__ void wsplit(const float* W, ushort* Wth, ushort* Wtl,
                                       int K, int N, int t) {
    int k = t / N, n = t - k * N;
    float v = W[t];
    ushort hv = f2bf_rne(v);
    float hf = bf2f(hv);
    ushort lv = f2bf_rne(v - hf);
    Wth[(size_t)n * K + k] = hv;
    Wtl[(size_t)n * K + k] = lv;
}

__global__ __launch_bounds__(256) void prep_all(
    const float* W11, ushort* W11h, ushort* W11l,
    const float* W12, ushort* W12h, ushort* W12l,
    const float* W21, ushort* W21h, ushort* W21l,
    const float* W22, ushort* W22h, ushort* W22l,
    const float* W31, ushort* W31h, ushort* W31l,
    const float* W32, ushort* W32h, ushort* W32l) {
    int t = blockIdx.x * blockDim.x + threadIdx.x;
    const int s1 = 128 * 256, s2 = s1 + 256 * 256, s3 = s2 + 256 * 128;
    const int s4 = s3 + 128 * 128, s5 = s4 + 128 * 64, s6 = s5 + 64 * 64;
    if (t < s1) wsplit(W11, W11h, W11l, 128, 256, t);
    else if (t < s2) wsplit(W12, W12h, W12l, 256, 256, t - s1);
    else if (t < s3) wsplit(W21, W21h, W21l, 256, 128, t - s2);
    else if (t < s4) wsplit(W22, W22h, W22l, 128, 128, t - s3);
    else if (t < s5) wsplit(W31, W31h, W31l, 128, 64, t - s4);
    else if (t < s6) wsplit(W32, W32h, W32l, 64, 64, t - s5);
}

// ---------------- fp32 -> bf16 convert (layer-1 gather copy) --------------
__global__ __launch_bounds__(256) void f32_to_bf16(const float* __restrict__ in,
                                                   ushort* __restrict__ out, long n4) {
    long i = (long)blockIdx.x * blockDim.x + threadIdx.x;
    long stride = (long)gridDim.x * blockDim.x;
    for (; i < n4; i += stride) {
        float4 v = ((const float4*)in)[i];
        ushort4 o;
        o.x = f2bf_rne(v.x);
        o.y = f2bf_rne(v.y);
        o.z = f2bf_rne(v.z);
        o.w = f2bf_rne(v.w);
        ((ushort4*)out)[i] = o;
    }
}

// ---------------- Fused GINE aggregation ----------------
// Per edge: acc += relu(proj(ea) + x_src). ea read sequentially from eacsr
// through SMEM (i is SGPR-born -> merged s_load_dwordx16), feeding 16
// pk_fma per edge (op_sel dword broadcast). 4-edge blocks: one per-lane
// csrc dword + 4 readlanes -> 4 batched row gathers; next block's csrc
// prefetched before the FMAs.
template <int D, int WPN>
__global__ __launch_bounds__(256) void gine_agg_kernel(
    const float* __restrict__ h, const ushort* __restrict__ hb,
    const float* __restrict__ eacsr,
    const int* __restrict__ row_start, const int* __restrict__ csrc,
    const float* __restrict__ We, const float* __restrict__ be,
    ushort* __restrict__ uhi, ushort* __restrict__ ulo, int N) {
    constexpr int NPB = 4 / WPN;  // nodes per 256-thread block
    const int lane = threadIdx.x & 63;
    const int wid = threadIdx.x >> 6;
    const int ch0 = (wid % WPN) * 128 + lane * 2;

    float2v w[16];
#pragma unroll
    for (int k = 0; k < 16; ++k) w[k] = *(const float2v*)&We[k * D + ch0];
    const float2v bias = *(const float2v*)&be[ch0];

    const int v = blockIdx.x * NPB + wid / WPN;
    if (v >= N) return;
    float2v z2; z2[0] = 0.f; z2[1] = 0.f;
    float2v acc = z2;

    int i = __builtin_amdgcn_readfirstlane(row_start[v]);
    const int e1 = __builtin_amdgcn_readfirstlane(row_start[v + 1]);

#define COMP1(qp, r)                                             \
    {                                                            \
        const u64* q_ = (qp);                                    \
        u64 a0 = q_[0], a1 = q_[1], a2 = q_[2], a3 = q_[3];      \
        u64 a4 = q_[4], a5 = q_[5], a6 = q_[6], a7 = q_[7];      \
        float2v p = bias;                                        \
        p = pkfma_lo(a0, w[0], p);  p = pkfma_hi(a0, w[1], p);   \
        p = pkfma_lo(a1, w[2], p);  p = pkfma_hi(a1, w[3], p);   \
        p = pkfma_lo(a2, w[4], p);  p = pkfma_hi(a2, w[5], p);   \
        p = pkfma_lo(a3, w[6], p);  p = pkfma_hi(a3, w[7], p);   \
        p = pkfma_lo(a4, w[8], p);  p = pkfma_hi(a4, w[9], p);   \
        p = pkfma_lo(a5, w[10], p); p = pkfma_hi(a5, w[11], p);  \
        p = pkfma_lo(a6, w[12], p); p = pkfma_hi(a6, w[13], p);  \
        float2v hv;                                              \
        hv[0] = __uint_as_float((r) << 16);                      \
        hv[1] = __uint_as_float((r) & 0xffff0000u);              \
        p = pkfma_lo(a7, w[14], p); p = pkfma_hi(a7, w[15], p);  \
        float2v m = p + hv;                                      \
        acc += __builtin_elementwise_max(m, z2);                 \
    }

    if (i + 4 <= e1) {
        int svn = csrc[i + (lane >> 4)];
        do {
            int sv = svn;
            if (i + 8 <= e1) svn = csrc[i + 4 + (lane >> 4)];
            const int s0 = __builtin_amdgcn_readlane(sv, 0);
            const int s1 = __builtin_amdgcn_readlane(sv, 16);
            const int s2 = __builtin_amdgcn_readlane(sv, 32);
            const int s3 = __builtin_amdgcn_readlane(sv, 48);
            // issue all 4 gathers first (longest latency)
            unsigned r0 = *(const unsigned*)&hb[(size_t)s0 * D + ch0];
            unsigned r1 = *(const unsigned*)&hb[(size_t)s1 * D + ch0];
            unsigned r2 = *(const unsigned*)&hb[(size_t)s2 * D + ch0];
            unsigned r3 = *(const unsigned*)&hb[(size_t)s3 * D + ch0];
            const u64* q = (const u64*)(eacsr + (size_t)i * 16);
            COMP1(q, r0);
            COMP1(q + 8, r1);
            COMP1(q + 16, r2);
            COMP1(q + 24, r3);
            i += 4;
        } while (i + 4 <= e1);
    }
    for (; i < e1; ++i) {  // tail (<=3 edges)
        const int se = __builtin_amdgcn_readfirstlane(csrc[i]);
        unsigned r = *(const unsigned*)&hb[(size_t)se * D + ch0];
        COMP1((const u64*)(eacsr + (size_t)i * 16), r);
    }
#undef COMP1

    // epilogue: u = h_v + acc -> bf16 hi/lo
    float2v sv2 = *(const float2v*)&h[(size_t)v * D + ch0];
    float u0 = sv2[0] + acc[0];
    float u1 = sv2[1] + acc[1];
    ushort h0 = f2bf_rne(u0);
    ushort h1 = f2bf_rne(u1);
    ushort l0 = f2bf_rne(u0 - bf2f(h0));
    ushort l1 = f2bf_rne(u1 - bf2f(h1));
    *(ushort2*)&uhi[(size_t)v * D + ch0] = make_ushort2(h0, h1);
    *(ushort2*)&ulo[(size_t)v * D + ch0] = make_ushort2(l0, l1);
}

// ---------------- Split-bf16 MFMA GEMM (+ optional fused BN stats) ---------
template <int WRITE_BF16, int STATS>
__global__ __launch_bounds__(256) void gemm_mfma(
    const ushort* __restrict__ Ah, const ushort* __restrict__ Al,
    const ushort* __restrict__ Bh, const ushort* __restrict__ Bl,
    const float* __restrict__ bias,
    float* __restrict__ Cf, ushort* __restrict__ Chi, ushort* __restrict__ Clo,
    float* __restrict__ stats, int Nreal,
    int N, int K, int relu) {
    __shared__ ushort sA[2][128][72];
    __shared__ ushort sB[2][64][72];
    const int tid = threadIdx.x;
    const int wave = tid >> 6, lane = tid & 63;
    const int lrow = lane & 15, lquad = lane >> 4;
    const int bm = blockIdx.y * 128;
    const int bn = blockIdx.x * 64;

    floatx4 acc[2][4];
#pragma unroll
    for (int i = 0; i < 2; ++i)
#pragma unroll
        for (int j = 0; j < 4; ++j) acc[i][j] = (floatx4)0.f;

    for (int k0 = 0; k0 < K; k0 += 64) {
        for (int s = tid; s < 1024; s += 256) {
            int row = s >> 3, c8 = (s & 7) * 8;
            size_t g = (size_t)(bm + row) * K + k0 + c8;
            *(int4*)&sA[0][row][c8] = *(const int4*)&Ah[g];
            *(int4*)&sA[1][row][c8] = *(const int4*)&Al[g];
        }
        for (int s = tid; s < 512; s += 256) {
            int row = s >> 3, c8 = (s & 7) * 8;
            size_t g = (size_t)(bn + row) * K + k0 + c8;
            *(int4*)&sB[0][row][c8] = *(const int4*)&Bh[g];
            *(int4*)&sB[1][row][c8] = *(const int4*)&Bl[g];
        }
        __syncthreads();
        const int rb = wave * 32;
#pragma unroll
        for (int kk = 0; kk < 2; ++kk) {
            int ko = kk * 32 + lquad * 8;
            short8 ah[2], al[2], bh[4], bl[4];
#pragma unroll
            for (int i = 0; i < 2; ++i) {
                ah[i] = *(const short8*)&sA[0][rb + i * 16 + lrow][ko];
                al[i] = *(const short8*)&sA[1][rb + i * 16 + lrow][ko];
            }
#pragma unroll
            for (int j = 0; j < 4; ++j) {
                bh[j] = *(const short8*)&sB[0][j * 16 + lrow][ko];
                bl[j] = *(const short8*)&sB[1][j * 16 + lrow][ko];
            }
#pragma unroll
            for (int i = 0; i < 2; ++i)
#pragma unroll
                for (int j = 0; j < 4; ++j) {
                    acc[i][j] = __builtin_amdgcn_mfma_f32_16x16x32_bf16(
                        ah[i], bh[j], acc[i][j], 0, 0, 0);
                    acc[i][j] = __builtin_amdgcn_mfma_f32_16x16x32_bf16(
                        ah[i], bl[j], acc[i][j], 0, 0, 0);
                    acc[i][j] = __builtin_amdgcn_mfma_f32_16x16x32_bf16(
                        al[i], bh[j], acc[i][j], 0, 0, 0);
                }
        }
        __syncthreads();
    }
    float sj[4] = {0.f, 0.f, 0.f, 0.f};
    float qj[4] = {0.f, 0.f, 0.f, 0.f};
#pragma unroll
    for (int i = 0; i < 2; ++i)
#pragma unroll
        for (int j = 0; j < 4; ++j) {
            int gc = bn + j * 16 + lrow;
            float bv = bias[gc];
#pragma unroll
            for (int r = 0; r < 4; ++r) {
                int gr = bm + wave * 32 + i * 16 + lquad * 4 + r;
                float v = acc[i][j][r] + bv;
                if (relu) v = fmaxf(v, 0.f);
                if (STATS && gr < Nreal) {
                    sj[j] += v;
                    qj[j] = fmaf(v, v, qj[j]);
                }
                if (WRITE_BF16) {
                    ushort hv = f2bf_rne(v);
                    ushort lv = f2bf_rne(v - bf2f(hv));
                    Chi[(size_t)gr * N + gc] = hv;
                    Clo[(size_t)gr * N + gc] = lv;
                } else {
                    Cf[(size_t)gr * N + gc] = v;
                }
            }
        }
    if (STATS) {
#pragma unroll
        for (int j = 0; j < 4; ++j) {
            float s = sj[j], q = qj[j];
            s += __shfl_xor(s, 16);
            s += __shfl_xor(s, 32);
            q += __shfl_xor(q, 16);
            q += __shfl_xor(q, 32);
            if (lquad == 0) {
                int gc = bn + j * 16 + lrow;
                atomicAdd(&stats[gc], s);
                atomicAdd(&stats[N + gc], q);
            }
        }
    }
}

// ---------------- BatchNorm apply (vectorized, + bf16 copy) ----------------
__global__ __launch_bounds__(256) void bn_apply_kernel(
    const float* __restrict__ r, float* __restrict__ h,
    ushort* __restrict__ hbout,
    const float* __restrict__ sums,
    const float* __restrict__ g, const float* __restrict__ bt,
    int N, int D, int Dm1) {
    int idx = blockIdx.x * blockDim.x + threadIdx.x;
    int total4 = N * D / 4;
    int stride = gridDim.x * blockDim.x;
    float invN = 1.0f / (float)N;
    for (; idx < total4; idx += stride) {
        int c = (idx * 4) & Dm1;
        float4 s4 = *(const float4*)&sums[c];
        float4 q4 = *(const float4*)&sums[D + c];
        float4 g4 = *(const float4*)&g[c];
        float4 b4 = *(const float4*)&bt[c];
        float4 r4 = ((const float4*)r)[idx];
        float4 o;
        {
            float mu = s4.x * invN;
            float var = fmaf(-mu, mu, q4.x * invN);
            o.x = (r4.x - mu) * (rsqrtf(var + 1e-5f) * g4.x) + b4.x;
            mu = s4.y * invN;
            var = fmaf(-mu, mu, q4.y * invN);
            o.y = (r4.y - mu) * (rsqrtf(var + 1e-5f) * g4.y) + b4.y;
            mu = s4.z * invN;
            var = fmaf(-mu, mu, q4.z * invN);
            o.z = (r4.z - mu) * (rsqrtf(var + 1e-5f) * g4.z) + b4.z;
            mu = s4.w * invN;
            var = fmaf(-mu, mu, q4.w * invN);
            o.w = (r4.w - mu) * (rsqrtf(var + 1e-5f) * g4.w) + b4.w;
        }
        ((float4*)h)[idx] = o;
        if (hbout) {
            ushort4 ob;
            ob.x = f2bf_rne(o.x);
            ob.y = f2bf_rne(o.y);
            ob.z = f2bf_rne(o.z);
            ob.w = f2bf_rne(o.w);
            ((ushort4*)hbout)[idx] = ob;
        }
    }
}

// ---------------- Head ----------------
__global__ void head_kernel(const float* __restrict__ h, const int* __restrict__ n_nodes,
                            const float* __restrict__ Wf1, const float* __restrict__ bf1,
                            const float* __restrict__ Wf2, const float* __restrict__ bf2,
                            float* __restrict__ out, int G) {
    int g = blockIdx.x * blockDim.x + threadIdx.x;
    if (g >= G) return;
    int s = 0;
    for (int i = 0; i <= g; ++i) s += n_nodes[i];
    const float* m = &h[(size_t)(s - 1) * 64];
    float o = bf2[0];
#pragma unroll 4
    for (int j = 0; j < 16; ++j) {
        float acc = bf1[j];
        for (int k = 0; k < 64; ++k) acc = fmaf(m[k], Wf1[k * 16 + j], acc);
        acc = fmaxf(acc, 0.f);
        o = fmaf(acc, Wf2[j], o);
    }
    out[g] = o;
}

extern "C" void kernel_launch(void* const* d_in, const int* in_sizes, int n_in,
                              void* d_out, int out_size, void* d_ws, size_t ws_size,
                              hipStream_t stream) {
    const float* x = (const float*)d_in[0];
    const float* ea = (const float*)d_in[1];
    const int* eidx = (const int*)d_in[2];
    const int* n_nodes = (const int*)d_in[3];
    const float* We1 = (const float*)d_in[4];
    const float* be1 = (const float*)d_in[5];
    const float* W11 = (const float*)d_in[6];
    const float* b11 = (const float*)d_in[7];
    const float* W12 = (const float*)d_in[8];
    const float* b12 = (const float*)d_in[9];
    const float* g1 = (const float*)d_in[10];
    const float* bt1 = (const float*)d_in[11];
    const float* We2 = (const float*)d_in[12];
    const float* be2 = (const float*)d_in[13];
    const float* W21 = (const float*)d_in[14];
    const float* b21 = (const float*)d_in[15];
    const float* W22 = (const float*)d_in[16];
    const float* b22 = (const float*)d_in[17];
    const float* g2 = (const float*)d_in[18];
    const float* bt2 = (const float*)d_in[19];
    const float* We3 = (const float*)d_in[20];
    const float* be3 = (const float*)d_in[21];
    const float* W31 = (const float*)d_in[22];
    const float* b31 = (const float*)d_in[23];
    const float* W32 = (const float*)d_in[24];
    const float* b32 = (const float*)d_in[25];
    const float* g3 = (const float*)d_in[26];
    const float* bt3 = (const float*)d_in[27];
    const float* Wf1 = (const float*)d_in[28];
    const float* bf1 = (const float*)d_in[29];
    const float* Wf2 = (const float*)d_in[30];
    const float* bf2 = (const float*)d_in[31];

    const int N = in_sizes[0] / 128;  // 50000
    const int E = in_sizes[2] / 2;    // 800000
    const int G = in_sizes[3];        // 500
    const int Mp = ((N + 127) / 128) * 128;  // 50048
    const int* srcp = eidx;
    const int* dstp = eidx + E;

    float* H = (float*)d_ws;            // Mp x 256 fp32
    float* UR = H + (size_t)Mp * 256;   // Mp x 256: u(hi/lo bf16) / r(fp32)
    float* TT = UR + (size_t)Mp * 256;  // Mp x 256: t(hi/lo bf16) / hb(bf16)
    float* stats1 = TT + (size_t)Mp * 256;  // 512
    float* stats2 = stats1 + 512;           // 256
    float* stats3 = stats2 + 256;           // 128
    int* deg = (int*)(stats3 + 128);        // N
    int* cursor = deg + N;                  // N
    int* row_start = cursor + N;            // N+1 (+1 pad)
    int* ceid = row_start + N + 2;          // E
    int* csrc = ceid + E;                   // E (+2 pad)
    ushort* wp = (ushort*)(csrc + E + 2);
    ushort* W11th = wp; wp += 128 * 256;
    ushort* W11tl = wp; wp += 128 * 256;
    ushort* W12th = wp; wp += 256 * 256;
    ushort* W12tl = wp; wp += 256 * 256;
    ushort* W21th = wp; wp += 256 * 128;
    ushort* W21tl = wp; wp += 256 * 128;
    ushort* W22th = wp; wp += 128 * 128;
    ushort* W22tl = wp; wp += 128 * 128;
    ushort* W31th = wp; wp += 128 * 64;
    ushort* W31tl = wp; wp += 128 * 64;
    ushort* W32th = wp; wp += 64 * 64;
    ushort* W32tl = wp; wp += 64 * 64;
    // align to 16B for eacsr
    float* eacsr;
    {
        size_t off = (size_t)((char*)wp - (char*)d_ws);
        off = (off + 15) & ~(size_t)15;
        eacsr = (float*)((char*)d_ws + off);  // E x 16 fp32 = 51.2 MB
    }

    hipMemsetAsync(stats1, 0, 896 * sizeof(float) + (size_t)2 * N * sizeof(int), stream);

    const int prepTot = 128 * 256 + 256 * 256 + 256 * 128 + 128 * 128 + 128 * 64 + 64 * 64;
    prep_all<<<(prepTot + 255) / 256, 256, 0, stream>>>(
        W11, W11th, W11tl, W12, W12th, W12tl, W21, W21th, W21tl,
        W22, W22th, W22tl, W31, W31th, W31tl, W32, W32th, W32tl);

    hist_kernel<<<3125, 256, 0, stream>>>(dstp, deg, E);
    scan_kernel<<<1, 1024, 0, stream>>>(deg, row_start, N);
    scatter_kernel<<<3125, 256, 0, stream>>>(srcp, dstp, row_start, cursor, ceid, csrc, E);
    eacsr_gather<<<12500, 256, 0, stream>>>(ea, ceid, eacsr, (long)E * 16);

    const int gy = Mp / 128;
    float* R = UR;
    ushort* HB = (ushort*)TT;  // bf16 gather copy lives in the (dead) TT region

    // ---------------- Layer 1: 128 -> 256 -> 256 ----------------
    {
        ushort* Uhi = (ushort*)UR; ushort* Ulo = Uhi + (size_t)Mp * 128;
        ushort* Thi = (ushort*)TT; ushort* Tlo = Thi + (size_t)Mp * 256;
        f32_to_bf16<<<2048, 256, 0, stream>>>(x, HB, (long)N * 128 / 4);
        gine_agg_kernel<128, 1><<<(N + 3) / 4, 256, 0, stream>>>(
            x, HB, eacsr, row_start, csrc, We1, be1, Uhi, Ulo, N);
        gemm_mfma<1, 0><<<dim3(4, gy), 256, 0, stream>>>(
            Uhi, Ulo, W11th, W11tl, b11, nullptr, Thi, Tlo, nullptr, 0, 256, 128, 1);
        gemm_mfma<0, 1><<<dim3(4, gy), 256, 0, stream>>>(
            Thi, Tlo, W12th, W12tl, b12, R, nullptr, nullptr, stats1, N, 256, 256, 1);
        bn_apply_kernel<<<2048, 256, 0, stream>>>(R, H, HB, stats1, g1, bt1, N, 256, 255);
    }

    // ---------------- Layer 2: 256 -> 128 -> 128 ----------------
    {
        ushort* Uhi = (ushort*)UR; ushort* Ulo = Uhi + (size_t)Mp * 256;
        ushort* Thi = (ushort*)TT; ushort* Tlo = Thi + (size_t)Mp * 128;
        gine_agg_kernel<256, 2><<<(N + 1) / 2, 256, 0, stream>>>(
            H, HB, eacsr, row_start, csrc, We2, be2, Uhi, Ulo, N);
        gemm_mfma<1, 0><<<dim3(2, gy), 256, 0, stream>>>(
            Uhi, Ulo, W21th, W21tl, b21, nullptr, Thi, Tlo, nullptr, 0, 128, 256, 1);
        gemm_mfma<0, 1><<<dim3(2, gy), 256, 0, stream>>>(
            Thi, Tlo, W22th, W22tl, b22, R, nullptr, nullptr, stats2, N, 128, 128, 1);
        bn_apply_kernel<<<2048, 256, 0, stream>>>(R, H, HB, stats2, g2, bt2, N, 128, 127);
    }

    // ---------------- Layer 3: 128 -> 64 -> 64 ----------------
    {
        ushort* Uhi = (ushort*)UR; ushort* Ulo = Uhi + (size_t)Mp * 128;
        ushort* Thi = (ushort*)TT; ushort* Tlo = Thi + (size_t)Mp * 64;
        gine_agg_kernel<128, 1><<<(N + 3) / 4, 256, 0, stream>>>(
            H, HB, eacsr, row_start, csrc, We3, be3, Uhi, Ulo, N);
        gemm_mfma<1, 0><<<dim3(1, gy), 256, 0, stream>>>(
            Uhi, Ulo, W31th, W31tl, b31, nullptr, Thi, Tlo, nullptr, 0, 64, 128, 1);
        gemm_mfma<0, 1><<<dim3(1, gy), 256, 0, stream>>>(
            Thi, Tlo, W32th, W32tl, b32, R, nullptr, nullptr, stats3, N, 64, 64, 1);
        bn_apply_kernel<<<2048, 256, 0, stream>>>(R, H, nullptr, stats3, g3, bt3, N, 64, 63);
    }

    // ---------------- Head ----------------
    head_kernel<<<(G + 255) / 256, 256, 0, stream>>>(H, n_nodes, Wf1, bf1, Wf2, bf2,
                                                     (float*)d_out, G);
}

// Round 6
// 952.810 us; speedup vs baseline: 1.3977x; 1.0173x over previous
//
#include <hip/hip_runtime.h>
#include <hip/hip_bf16.h>

// ---------------------------------------------------------------------------
// GIN0 (GINE x3 + BN + head) forward.
// R1: CSR + per-node register aggregation (no atomics in hot path).
// R3: node MLP GEMMs on MFMA via split-bf16 (hi+lo, 3-pass).
// R5: BN stats fused into GEMM2 epilogue; single prep kernel.
// R6: gathers read a bf16 copy of h; self-term fp32.
// R8: WPN waves/node so We slice stays VGPR-resident.
// R15: agg VALU diet. R14's "s"-constrained pkfma forced ~16
//      v_readfirstlane/edge (ea loads are VMEM; SGPR operands must be
//      materialized). Fix: v_pk_fma_f32 src0 as VGPR pair ("v") — op_sel
//      broadcast works identically. eacsr read via ONE base pointer per
//      4-edge block + immediate offsets (compiler merges ep[0..15] into
//      global_load_dwordx4 offset:N) — ~1 VALU/block of address math.
//      ea software-pipelined 1 edge ahead (<=32 VGPR in flight).
//      scan_kernel: serial 1024-loop -> LDS Hillis-Steele.
// ---------------------------------------------------------------------------

typedef __attribute__((ext_vector_type(8))) short short8;
typedef __attribute__((ext_vector_type(4))) float floatx4;
typedef __attribute__((ext_vector_type(2))) float float2v;
typedef unsigned long long u64;

// p += bcast(lo dword of e) * w   (packed fp32, VGPR-pair scalar operand)
__device__ __forceinline__ float2v pkfma_lo(u64 e, float2v w, float2v p) {
    asm("v_pk_fma_f32 %0, %1, %2, %0 op_sel:[0,0,0] op_sel_hi:[0,1,1]"
        : "+v"(p) : "v"(e), "v"(w));
    return p;
}

// p += bcast(hi dword of e) * w
__device__ __forceinline__ float2v pkfma_hi(u64 e, float2v w, float2v p) {
    asm("v_pk_fma_f32 %0, %1, %2, %0 op_sel:[1,0,0] op_sel_hi:[1,1,1]"
        : "+v"(p) : "v"(e), "v"(w));
    return p;
}

__device__ __forceinline__ ushort f2bf_rne(float x) {
    unsigned u = __float_as_uint(x);
    unsigned r = (u + 0x7FFFu + ((u >> 16) & 1u)) >> 16;
    return (ushort)r;
}

__device__ __forceinline__ float bf2f(ushort u) {
    return __uint_as_float(((unsigned)u) << 16);
}

// ---------------- CSR build ----------------

__global__ __launch_bounds__(256) void hist_kernel(const int* __restrict__ dst,
                                                   int* __restrict__ deg, int E) {
    int i = blockIdx.x * blockDim.x + threadIdx.x;
    int stride = gridDim.x * blockDim.x;
    for (; i < E; i += stride) atomicAdd(&deg[dst[i]], 1);
}

__global__ __launch_bounds__(1024) void scan_kernel(const int* __restrict__ deg,
                                                    int* __restrict__ row_start, int N) {
    __shared__ int part[1024];
    int tid = threadIdx.x;
    int per = (N + 1023) / 1024;
    int start = tid * per;
    int end = min(start + per, N);
    int s = 0;
    for (int i = start; i < end; ++i) s += deg[i];
    part[tid] = s;
    __syncthreads();
    // Hillis-Steele inclusive scan over the 1024 partials
    for (int off = 1; off < 1024; off <<= 1) {
        int t = (tid >= off) ? part[tid - off] : 0;
        __syncthreads();
        part[tid] += t;
        __syncthreads();
    }
    int run = part[tid] - s;  // exclusive prefix
    for (int i = start; i < end; ++i) {
        row_start[i] = run;
        run += deg[i];
    }
    if (tid == 1023) row_start[N] = part[1023];
}

__global__ __launch_bounds__(256) void scatter_kernel(
    const int* __restrict__ src, const int* __restrict__ dst,
    const int* __restrict__ row_start, int* __restrict__ cursor,
    int* __restrict__ ceid, int* __restrict__ csrc, int E) {
    int i = blockIdx.x * blockDim.x + threadIdx.x;
    int stride = gridDim.x * blockDim.x;
    for (; i < E; i += stride) {
        int v = dst[i];
        int p = row_start[v] + atomicAdd(&cursor[v], 1);
        ceid[p] = i;
        csrc[p] = src[i];
    }
}

// ---------------- ea -> CSR order (fp32 stream for the agg loop) ----------
__global__ __launch_bounds__(256) void eacsr_gather(const float* __restrict__ ea,
                                                    const int* __restrict__ ceid,
                                                    float* __restrict__ eacsr, long total) {
    long t = (long)blockIdx.x * 256 + threadIdx.x;
    long stride = (long)gridDim.x * 256;
    for (; t < total; t += stride) {
        long p = t >> 4;
        int c = (int)(t & 15);
        eacsr[t] = ea[(size_t)ceid[p] * 16 + c];
    }
}

// ---------------- Weight prep (node MLP GEMM weights) ----------------
__device__ __forceinline__ void wsplit(const float* W, ushort* Wth, ushort* Wtl,
                                       int K, int N, int t) {
    int k = t / N, n = t - k * N;
    float v = W[t];
    ushort hv = f2bf_rne(v);
    float hf = bf2f(hv);
    ushort lv = f2bf_rne(v - hf);
    Wth[(size_t)n * K + k] = hv;
    Wtl[(size_t)n * K + k] = lv;
}

__global__ __launch_bounds__(256) void prep_all(
    const float* W11, ushort* W11h, ushort* W11l,
    const float* W12, ushort* W12h, ushort* W12l,
    const float* W21, ushort* W21h, ushort* W21l,
    const float* W22, ushort* W22h, ushort* W22l,
    const float* W31, ushort* W31h, ushort* W31l,
    const float* W32, ushort* W32h, ushort* W32l) {
    int t = blockIdx.x * blockDim.x + threadIdx.x;
    const int s1 = 128 * 256, s2 = s1 + 256 * 256, s3 = s2 + 256 * 128;
    const int s4 = s3 + 128 * 128, s5 = s4 + 128 * 64, s6 = s5 + 64 * 64;
    if (t < s1) wsplit(W11, W11h, W11l, 128, 256, t);
    else if (t < s2) wsplit(W12, W12h, W12l, 256, 256, t - s1);
    else if (t < s3) wsplit(W21, W21h, W21l, 256, 128, t - s2);
    else if (t < s4) wsplit(W22, W22h, W22l, 128, 128, t - s3);
    else if (t < s5) wsplit(W31, W31h, W31l, 128, 64, t - s4);
    else if (t < s6) wsplit(W32, W32h, W32l, 64, 64, t - s5);
}

// ---------------- fp32 -> bf16 convert (layer-1 gather copy) --------------
__global__ __launch_bounds__(256) void f32_to_bf16(const float* __restrict__ in,
                                                   ushort* __restrict__ out, long n4) {
    long i = (long)blockIdx.x * blockDim.x + threadIdx.x;
    long stride = (long)gridDim.x * blockDim.x;
    for (; i < n4; i += stride) {
        float4 v = ((const float4*)in)[i];
        ushort4 o;
        o.x = f2bf_rne(v.x);
        o.y = f2bf_rne(v.y);
        o.z = f2bf_rne(v.z);
        o.w = f2bf_rne(v.w);
        ((ushort4*)out)[i] = o;
    }
}

// ---------------- Fused GINE aggregation ----------------
// Per edge: acc += relu(proj(ea) + x_src). ea read from eacsr via one base
// pointer per 4-edge block + immediate offsets (16x dwordx4), pipelined one
// edge ahead; v_pk_fma_f32 with VGPR-pair operand (op_sel broadcast).
// 4-edge blocks: one per-lane csrc dword + 4 readlanes -> 4 batched gathers.
template <int D, int WPN>
__global__ __launch_bounds__(256) void gine_agg_kernel(
    const float* __restrict__ h, const ushort* __restrict__ hb,
    const float* __restrict__ eacsr,
    const int* __restrict__ row_start, const int* __restrict__ csrc,
    const float* __restrict__ We, const float* __restrict__ be,
    ushort* __restrict__ uhi, ushort* __restrict__ ulo, int N) {
    constexpr int NPB = 4 / WPN;  // nodes per 256-thread block
    const int lane = threadIdx.x & 63;
    const int wid = threadIdx.x >> 6;
    const int ch0 = (wid % WPN) * 128 + lane * 2;

    float2v w[16];
#pragma unroll
    for (int k = 0; k < 16; ++k) w[k] = *(const float2v*)&We[k * D + ch0];
    const float2v bias = *(const float2v*)&be[ch0];

    const int v = blockIdx.x * NPB + wid / WPN;
    if (v >= N) return;
    float2v z2; z2[0] = 0.f; z2[1] = 0.f;
    float2v acc = z2;

    int i = __builtin_amdgcn_readfirstlane(row_start[v]);
    const int e1 = __builtin_amdgcn_readfirstlane(row_start[v + 1]);

    // COMP4: one edge = 4 float4 (16 ea dims), via 8 u64 pkfma pairs
#define COMP4(F0, F1, F2, F3, r)                                   \
    {                                                              \
        const u64* qa = (const u64*)&F0;                           \
        const u64* qb = (const u64*)&F1;                           \
        const u64* qc = (const u64*)&F2;                           \
        const u64* qd = (const u64*)&F3;                           \
        float2v p = bias;                                          \
        p = pkfma_lo(qa[0], w[0], p);  p = pkfma_hi(qa[0], w[1], p);  \
        p = pkfma_lo(qa[1], w[2], p);  p = pkfma_hi(qa[1], w[3], p);  \
        p = pkfma_lo(qb[0], w[4], p);  p = pkfma_hi(qb[0], w[5], p);  \
        p = pkfma_lo(qb[1], w[6], p);  p = pkfma_hi(qb[1], w[7], p);  \
        p = pkfma_lo(qc[0], w[8], p);  p = pkfma_hi(qc[0], w[9], p);  \
        p = pkfma_lo(qc[1], w[10], p); p = pkfma_hi(qc[1], w[11], p); \
        p = pkfma_lo(qd[0], w[12], p); p = pkfma_hi(qd[0], w[13], p); \
        float2v hv;                                                \
        hv[0] = __uint_as_float((r) << 16);                        \
        hv[1] = __uint_as_float((r) & 0xffff0000u);                \
        p = pkfma_lo(qd[1], w[14], p); p = pkfma_hi(qd[1], w[15], p); \
        float2v m = p + hv;                                        \
        acc += __builtin_elementwise_max(m, z2);                   \
    }

    if (i + 4 <= e1) {
        int svn = csrc[i + (lane >> 4)];
        do {
            int sv = svn;
            if (i + 8 <= e1) svn = csrc[i + 4 + (lane >> 4)];
            const int s0 = __builtin_amdgcn_readlane(sv, 0);
            const int s1 = __builtin_amdgcn_readlane(sv, 16);
            const int s2 = __builtin_amdgcn_readlane(sv, 32);
            const int s3 = __builtin_amdgcn_readlane(sv, 48);
            // issue all 4 gathers first (longest latency)
            unsigned r0 = *(const unsigned*)&hb[(size_t)s0 * D + ch0];
            unsigned r1 = *(const unsigned*)&hb[(size_t)s1 * D + ch0];
            unsigned r2 = *(const unsigned*)&hb[(size_t)s2 * D + ch0];
            unsigned r3 = *(const unsigned*)&hb[(size_t)s3 * D + ch0];
            // ea: single base, immediate offsets; pipelined 1 edge ahead
            const float4* ep = (const float4*)(eacsr + (size_t)i * 16);
            float4 f0 = ep[0], f1 = ep[1], f2 = ep[2], f3 = ep[3];      // edge i
            float4 g0 = ep[4], g1 = ep[5], g2 = ep[6], g3 = ep[7];      // edge i+1
            COMP4(f0, f1, f2, f3, r0);
            f0 = ep[8]; f1 = ep[9]; f2 = ep[10]; f3 = ep[11];           // edge i+2
            COMP4(g0, g1, g2, g3, r1);
            g0 = ep[12]; g1 = ep[13]; g2 = ep[14]; g3 = ep[15];         // edge i+3
            COMP4(f0, f1, f2, f3, r2);
            COMP4(g0, g1, g2, g3, r3);
            i += 4;
        } while (i + 4 <= e1);
    }
    for (; i < e1; ++i) {  // tail (<=3 edges)
        const int se = __builtin_amdgcn_readfirstlane(csrc[i]);
        unsigned r = *(const unsigned*)&hb[(size_t)se * D + ch0];
        const float4* ep = (const float4*)(eacsr + (size_t)i * 16);
        float4 f0 = ep[0], f1 = ep[1], f2 = ep[2], f3 = ep[3];
        COMP4(f0, f1, f2, f3, r);
    }
#undef COMP4

    // epilogue: u = h_v + acc -> bf16 hi/lo
    float2v sv2 = *(const float2v*)&h[(size_t)v * D + ch0];
    float u0 = sv2[0] + acc[0];
    float u1 = sv2[1] + acc[1];
    ushort h0 = f2bf_rne(u0);
    ushort h1 = f2bf_rne(u1);
    ushort l0 = f2bf_rne(u0 - bf2f(h0));
    ushort l1 = f2bf_rne(u1 - bf2f(h1));
    *(ushort2*)&uhi[(size_t)v * D + ch0] = make_ushort2(h0, h1);
    *(ushort2*)&ulo[(size_t)v * D + ch0] = make_ushort2(l0, l1);
}

// ---------------- Split-bf16 MFMA GEMM (+ optional fused BN stats) ---------
template <int WRITE_BF16, int STATS>
__global__ __launch_bounds__(256) void gemm_mfma(
    const ushort* __restrict__ Ah, const ushort* __restrict__ Al,
    const ushort* __restrict__ Bh, const ushort* __restrict__ Bl,
    const float* __restrict__ bias,
    float* __restrict__ Cf, ushort* __restrict__ Chi, ushort* __restrict__ Clo,
    float* __restrict__ stats, int Nreal,
    int N, int K, int relu) {
    __shared__ ushort sA[2][128][72];
    __shared__ ushort sB[2][64][72];
    const int tid = threadIdx.x;
    const int wave = tid >> 6, lane = tid & 63;
    const int lrow = lane & 15, lquad = lane >> 4;
    const int bm = blockIdx.y * 128;
    const int bn = blockIdx.x * 64;

    floatx4 acc[2][4];
#pragma unroll
    for (int i = 0; i < 2; ++i)
#pragma unroll
        for (int j = 0; j < 4; ++j) acc[i][j] = (floatx4)0.f;

    for (int k0 = 0; k0 < K; k0 += 64) {
        for (int s = tid; s < 1024; s += 256) {
            int row = s >> 3, c8 = (s & 7) * 8;
            size_t g = (size_t)(bm + row) * K + k0 + c8;
            *(int4*)&sA[0][row][c8] = *(const int4*)&Ah[g];
            *(int4*)&sA[1][row][c8] = *(const int4*)&Al[g];
        }
        for (int s = tid; s < 512; s += 256) {
            int row = s >> 3, c8 = (s & 7) * 8;
            size_t g = (size_t)(bn + row) * K + k0 + c8;
            *(int4*)&sB[0][row][c8] = *(const int4*)&Bh[g];
            *(int4*)&sB[1][row][c8] = *(const int4*)&Bl[g];
        }
        __syncthreads();
        const int rb = wave * 32;
#pragma unroll
        for (int kk = 0; kk < 2; ++kk) {
            int ko = kk * 32 + lquad * 8;
            short8 ah[2], al[2], bh[4], bl[4];
#pragma unroll
            for (int i = 0; i < 2; ++i) {
                ah[i] = *(const short8*)&sA[0][rb + i * 16 + lrow][ko];
                al[i] = *(const short8*)&sA[1][rb + i * 16 + lrow][ko];
            }
#pragma unroll
            for (int j = 0; j < 4; ++j) {
                bh[j] = *(const short8*)&sB[0][j * 16 + lrow][ko];
                bl[j] = *(const short8*)&sB[1][j * 16 + lrow][ko];
            }
#pragma unroll
            for (int i = 0; i < 2; ++i)
#pragma unroll
                for (int j = 0; j < 4; ++j) {
                    acc[i][j] = __builtin_amdgcn_mfma_f32_16x16x32_bf16(
                        ah[i], bh[j], acc[i][j], 0, 0, 0);
                    acc[i][j] = __builtin_amdgcn_mfma_f32_16x16x32_bf16(
                        ah[i], bl[j], acc[i][j], 0, 0, 0);
                    acc[i][j] = __builtin_amdgcn_mfma_f32_16x16x32_bf16(
                        al[i], bh[j], acc[i][j], 0, 0, 0);
                }
        }
        __syncthreads();
    }
    float sj[4] = {0.f, 0.f, 0.f, 0.f};
    float qj[4] = {0.f, 0.f, 0.f, 0.f};
#pragma unroll
    for (int i = 0; i < 2; ++i)
#pragma unroll
        for (int j = 0; j < 4; ++j) {
            int gc = bn + j * 16 + lrow;
            float bv = bias[gc];
#pragma unroll
            for (int r = 0; r < 4; ++r) {
                int gr = bm + wave * 32 + i * 16 + lquad * 4 + r;
                float v = acc[i][j][r] + bv;
                if (relu) v = fmaxf(v, 0.f);
                if (STATS && gr < Nreal) {
                    sj[j] += v;
                    qj[j] = fmaf(v, v, qj[j]);
                }
                if (WRITE_BF16) {
                    ushort hv = f2bf_rne(v);
                    ushort lv = f2bf_rne(v - bf2f(hv));
                    Chi[(size_t)gr * N + gc] = hv;
                    Clo[(size_t)gr * N + gc] = lv;
                } else {
                    Cf[(size_t)gr * N + gc] = v;
                }
            }
        }
    if (STATS) {
#pragma unroll
        for (int j = 0; j < 4; ++j) {
            float s = sj[j], q = qj[j];
            s += __shfl_xor(s, 16);
            s += __shfl_xor(s, 32);
            q += __shfl_xor(q, 16);
            q += __shfl_xor(q, 32);
            if (lquad == 0) {
                int gc = bn + j * 16 + lrow;
                atomicAdd(&stats[gc], s);
                atomicAdd(&stats[N + gc], q);
            }
        }
    }
}

// ---------------- BatchNorm apply (vectorized, + bf16 copy) ----------------
__global__ __launch_bounds__(256) void bn_apply_kernel(
    const float* __restrict__ r, float* __restrict__ h,
    ushort* __restrict__ hbout,
    const float* __restrict__ sums,
    const float* __restrict__ g, const float* __restrict__ bt,
    int N, int D, int Dm1) {
    int idx = blockIdx.x * blockDim.x + threadIdx.x;
    int total4 = N * D / 4;
    int stride = gridDim.x * blockDim.x;
    float invN = 1.0f / (float)N;
    for (; idx < total4; idx += stride) {
        int c = (idx * 4) & Dm1;
        float4 s4 = *(const float4*)&sums[c];
        float4 q4 = *(const float4*)&sums[D + c];
        float4 g4 = *(const float4*)&g[c];
        float4 b4 = *(const float4*)&bt[c];
        float4 r4 = ((const float4*)r)[idx];
        float4 o;
        {
            float mu = s4.x * invN;
            float var = fmaf(-mu, mu, q4.x * invN);
            o.x = (r4.x - mu) * (rsqrtf(var + 1e-5f) * g4.x) + b4.x;
            mu = s4.y * invN;
            var = fmaf(-mu, mu, q4.y * invN);
            o.y = (r4.y - mu) * (rsqrtf(var + 1e-5f) * g4.y) + b4.y;
            mu = s4.z * invN;
            var = fmaf(-mu, mu, q4.z * invN);
            o.z = (r4.z - mu) * (rsqrtf(var + 1e-5f) * g4.z) + b4.z;
            mu = s4.w * invN;
            var = fmaf(-mu, mu, q4.w * invN);
            o.w = (r4.w - mu) * (rsqrtf(var + 1e-5f) * g4.w) + b4.w;
        }
        ((float4*)h)[idx] = o;
        if (hbout) {
            ushort4 ob;
            ob.x = f2bf_rne(o.x);
            ob.y = f2bf_rne(o.y);
            ob.z = f2bf_rne(o.z);
            ob.w = f2bf_rne(o.w);
            ((ushort4*)hbout)[idx] = ob;
        }
    }
}

// ---------------- Head ----------------
__global__ void head_kernel(const float* __restrict__ h, const int* __restrict__ n_nodes,
                            const float* __restrict__ Wf1, const float* __restrict__ bf1,
                            const float* __restrict__ Wf2, const float* __restrict__ bf2,
                            float* __restrict__ out, int G) {
    int g = blockIdx.x * blockDim.x + threadIdx.x;
    if (g >= G) return;
    int s = 0;
    for (int i = 0; i <= g; ++i) s += n_nodes[i];
    const float* m = &h[(size_t)(s - 1) * 64];
    float o = bf2[0];
#pragma unroll 4
    for (int j = 0; j < 16; ++j) {
        float acc = bf1[j];
        for (int k = 0; k < 64; ++k) acc = fmaf(m[k], Wf1[k * 16 + j], acc);
        acc = fmaxf(acc, 0.f);
        o = fmaf(acc, Wf2[j], o);
    }
    out[g] = o;
}

extern "C" void kernel_launch(void* const* d_in, const int* in_sizes, int n_in,
                              void* d_out, int out_size, void* d_ws, size_t ws_size,
                              hipStream_t stream) {
    const float* x = (const float*)d_in[0];
    const float* ea = (const float*)d_in[1];
    const int* eidx = (const int*)d_in[2];
    const int* n_nodes = (const int*)d_in[3];
    const float* We1 = (const float*)d_in[4];
    const float* be1 = (const float*)d_in[5];
    const float* W11 = (const float*)d_in[6];
    const float* b11 = (const float*)d_in[7];
    const float* W12 = (const float*)d_in[8];
    const float* b12 = (const float*)d_in[9];
    const float* g1 = (const float*)d_in[10];
    const float* bt1 = (const float*)d_in[11];
    const float* We2 = (const float*)d_in[12];
    const float* be2 = (const float*)d_in[13];
    const float* W21 = (const float*)d_in[14];
    const float* b21 = (const float*)d_in[15];
    const float* W22 = (const float*)d_in[16];
    const float* b22 = (const float*)d_in[17];
    const float* g2 = (const float*)d_in[18];
    const float* bt2 = (const float*)d_in[19];
    const float* We3 = (const float*)d_in[20];
    const float* be3 = (const float*)d_in[21];
    const float* W31 = (const float*)d_in[22];
    const float* b31 = (const float*)d_in[23];
    const float* W32 = (const float*)d_in[24];
    const float* b32 = (const float*)d_in[25];
    const float* g3 = (const float*)d_in[26];
    const float* bt3 = (const float*)d_in[27];
    const float* Wf1 = (const float*)d_in[28];
    const float* bf1 = (const float*)d_in[29];
    const float* Wf2 = (const float*)d_in[30];
    const float* bf2 = (const float*)d_in[31];

    const int N = in_sizes[0] / 128;  // 50000
    const int E = in_sizes[2] / 2;    // 800000
    const int G = in_sizes[3];        // 500
    const int Mp = ((N + 127) / 128) * 128;  // 50048
    const int* srcp = eidx;
    const int* dstp = eidx + E;

    float* H = (float*)d_ws;            // Mp x 256 fp32
    float* UR = H + (size_t)Mp * 256;   // Mp x 256: u(hi/lo bf16) / r(fp32)
    float* TT = UR + (size_t)Mp * 256;  // Mp x 256: t(hi/lo bf16) / hb(bf16)
    float* stats1 = TT + (size_t)Mp * 256;  // 512
    float* stats2 = stats1 + 512;           // 256
    float* stats3 = stats2 + 256;           // 128
    int* deg = (int*)(stats3 + 128);        // N
    int* cursor = deg + N;                  // N
    int* row_start = cursor + N;            // N+1 (+1 pad)
    int* ceid = row_start + N + 2;          // E
    int* csrc = ceid + E;                   // E (+2 pad)
    ushort* wp = (ushort*)(csrc + E + 2);
    ushort* W11th = wp; wp += 128 * 256;
    ushort* W11tl = wp; wp += 128 * 256;
    ushort* W12th = wp; wp += 256 * 256;
    ushort* W12tl = wp; wp += 256 * 256;
    ushort* W21th = wp; wp += 256 * 128;
    ushort* W21tl = wp; wp += 256 * 128;
    ushort* W22th = wp; wp += 128 * 128;
    ushort* W22tl = wp; wp += 128 * 128;
    ushort* W31th = wp; wp += 128 * 64;
    ushort* W31tl = wp; wp += 128 * 64;
    ushort* W32th = wp; wp += 64 * 64;
    ushort* W32tl = wp; wp += 64 * 64;
    // align to 16B for eacsr
    float* eacsr;
    {
        size_t off = (size_t)((char*)wp - (char*)d_ws);
        off = (off + 15) & ~(size_t)15;
        eacsr = (float*)((char*)d_ws + off);  // E x 16 fp32 = 51.2 MB
    }

    hipMemsetAsync(stats1, 0, 896 * sizeof(float) + (size_t)2 * N * sizeof(int), stream);

    const int prepTot = 128 * 256 + 256 * 256 + 256 * 128 + 128 * 128 + 128 * 64 + 64 * 64;
    prep_all<<<(prepTot + 255) / 256, 256, 0, stream>>>(
        W11, W11th, W11tl, W12, W12th, W12tl, W21, W21th, W21tl,
        W22, W22th, W22tl, W31, W31th, W31tl, W32, W32th, W32tl);

    hist_kernel<<<3125, 256, 0, stream>>>(dstp, deg, E);
    scan_kernel<<<1, 1024, 0, stream>>>(deg, row_start, N);
    scatter_kernel<<<3125, 256, 0, stream>>>(srcp, dstp, row_start, cursor, ceid, csrc, E);
    eacsr_gather<<<12500, 256, 0, stream>>>(ea, ceid, eacsr, (long)E * 16);

    const int gy = Mp / 128;
    float* R = UR;
    ushort* HB = (ushort*)TT;  // bf16 gather copy lives in the (dead) TT region

    // ---------------- Layer 1: 128 -> 256 -> 256 ----------------
    {
        ushort* Uhi = (ushort*)UR; ushort* Ulo = Uhi + (size_t)Mp * 128;
        ushort* Thi = (ushort*)TT; ushort* Tlo = Thi + (size_t)Mp * 256;
        f32_to_bf16<<<2048, 256, 0, stream>>>(x, HB, (long)N * 128 / 4);
        gine_agg_kernel<128, 1><<<(N + 3) / 4, 256, 0, stream>>>(
            x, HB, eacsr, row_start, csrc, We1, be1, Uhi, Ulo, N);
        gemm_mfma<1, 0><<<dim3(4, gy), 256, 0, stream>>>(
            Uhi, Ulo, W11th, W11tl, b11, nullptr, Thi, Tlo, nullptr, 0, 256, 128, 1);
        gemm_mfma<0, 1><<<dim3(4, gy), 256, 0, stream>>>(
            Thi, Tlo, W12th, W12tl, b12, R, nullptr, nullptr, stats1, N, 256, 256, 1);
        bn_apply_kernel<<<2048, 256, 0, stream>>>(R, H, HB, stats1, g1, bt1, N, 256, 255);
    }

    // ---------------- Layer 2: 256 -> 128 -> 128 ----------------
    {
        ushort* Uhi = (ushort*)UR; ushort* Ulo = Uhi + (size_t)Mp * 256;
        ushort* Thi = (ushort*)TT; ushort* Tlo = Thi + (size_t)Mp * 128;
        gine_agg_kernel<256, 2><<<(N + 1) / 2, 256, 0, stream>>>(
            H, HB, eacsr, row_start, csrc, We2, be2, Uhi, Ulo, N);
        gemm_mfma<1, 0><<<dim3(2, gy), 256, 0, stream>>>(
            Uhi, Ulo, W21th, W21tl, b21, nullptr, Thi, Tlo, nullptr, 0, 128, 256, 1);
        gemm_mfma<0, 1><<<dim3(2, gy), 256, 0, stream>>>(
            Thi, Tlo, W22th, W22tl, b22, R, nullptr, nullptr, stats2, N, 128, 128, 1);
        bn_apply_kernel<<<2048, 256, 0, stream>>>(R, H, HB, stats2, g2, bt2, N, 128, 127);
    }

    // ---------------- Layer 3: 128 -> 64 -> 64 ----------------
    {
        ushort* Uhi = (ushort*)UR; ushort* Ulo = Uhi + (size_t)Mp * 128;
        ushort* Thi = (ushort*)TT; ushort* Tlo = Thi + (size_t)Mp * 64;
        gine_agg_kernel<128, 1><<<(N + 3) / 4, 256, 0, stream>>>(
            H, HB, eacsr, row_start, csrc, We3, be3, Uhi, Ulo, N);
        gemm_mfma<1, 0><<<dim3(1, gy), 256, 0, stream>>>(
            Uhi, Ulo, W31th, W31tl, b31, nullptr, Thi, Tlo, nullptr, 0, 64, 128, 1);
        gemm_mfma<0, 1><<<dim3(1, gy), 256, 0, stream>>>(
            Thi, Tlo, W32th, W32tl, b32, R, nullptr, nullptr, stats3, N, 64, 64, 1);
        bn_apply_kernel<<<2048, 256, 0, stream>>>(R, H, nullptr, stats3, g3, bt3, N, 64, 63);
    }

    // ---------------- Head ----------------
    head_kernel<<<(G + 255) / 256, 256, 0, stream>>>(H, n_nodes, Wf1, bf1, Wf2, bf2,
                                                     (float*)d_out, G);
}